// Round 5
// baseline (270.202 us; speedup 1.0000x reference)
//
#include <hip/hip_runtime.h>
#include <hip/hip_bf16.h>
#include <math.h>

#define NB 16
#define NS 1024
#define NM 256
#define NH 8
#define NDK 32
#define NL 2

typedef __attribute__((ext_vector_type(4))) float f32x4;
typedef __attribute__((ext_vector_type(8))) short bf16x8;
typedef __attribute__((ext_vector_type(4))) short bf16x4u;

#if __has_builtin(__builtin_amdgcn_exp2f)
#define EXP2F(x) __builtin_amdgcn_exp2f(x)
#else
#define EXP2F(x) exp2f(x)
#endif

__device__ __forceinline__ unsigned short f2bf(float f) {
  unsigned int u = __builtin_bit_cast(unsigned int, f);
  unsigned int r = u + 0x7fffu + ((u >> 16) & 1u);
  return (unsigned short)(r >> 16);
}
__device__ __forceinline__ float bf2f(unsigned short h) {
  unsigned int u = ((unsigned int)h) << 16;
  return __builtin_bit_cast(float, u);
}

// ---------------------------------------------------------------------------
// Pack (smask || adj==0) and (smask) into bitmasks, 1 bit per (b,i,j).
__global__ __launch_bounds__(256) void maskpack_kernel(
    const int* __restrict__ adj, const int* __restrict__ sm,
    unsigned int* __restrict__ pkc, unsigned int* __restrict__ pks)
{
  int t = blockIdx.x * 256 + threadIdx.x;
  long base = (long)t * 32;
  const int4* a4 = (const int4*)(adj + base);
  const int4* m4 = (const int4*)(sm + base);
  union { int4 v[8]; int b[32]; } au, mu;
#pragma unroll
  for (int q = 0; q < 8; ++q) { au.v[q] = a4[q]; mu.v[q] = m4[q]; }
  unsigned int wc = 0, wsb = 0;
#pragma unroll
  for (int e = 0; e < 32; ++e) {
    unsigned int msk = mu.b[e] ? 1u : 0u;
    unsigned int cmb = (mu.b[e] || au.b[e] == 0) ? 1u : 0u;
    wsb |= msk << e;
    wc  |= cmb << e;
  }
  pkc[t] = wc; pks[t] = wsb;
}

// ---------------------------------------------------------------------------
// Projection GEMM -> Pt[b][h][d][s] (bf16), 64x64 tile, 4 waves.
__global__ __launch_bounds__(256) void proj_kernel(
    const float* __restrict__ x,        // (B*S, M)
    const float* __restrict__ pw,       // (H, M, DK) this layer
    const float* __restrict__ pb,       // (H*DK)
    unsigned short* __restrict__ Pt)    // (B,H,DK,S)
{
  __shared__ unsigned short As[64][40];
  __shared__ unsigned short Bs[64][40];

  int ct = blockIdx.x;
  int rt = blockIdx.y;
  int t = threadIdx.x;
  int w = t >> 6, lane = t & 63;
  int il = lane & 15, g4 = lane >> 4;
  int wi = w >> 1, wc = w & 1;

  f32x4 acc[2][2] = {};

  int arow = t >> 2, akoff = (t & 3) * 8;
  int bcol = t & 63, bk0 = (t >> 6) * 8;
  int hd = ct * 64 + bcol;
  int h = hd >> 5, d = hd & 31;

  for (int k0 = 0; k0 < NM; k0 += 32) {
    const float* xp = x + (size_t)(rt * 64 + arow) * NM + k0 + akoff;
    f32x4 v0 = *(const f32x4*)xp;
    f32x4 v1 = *(const f32x4*)(xp + 4);
    bf16x8 av;
    av[0] = f2bf(v0[0]); av[1] = f2bf(v0[1]); av[2] = f2bf(v0[2]); av[3] = f2bf(v0[3]);
    av[4] = f2bf(v1[0]); av[5] = f2bf(v1[1]); av[6] = f2bf(v1[2]); av[7] = f2bf(v1[3]);
    *(bf16x8*)&As[arow][akoff] = av;
    const float* wp = pw + (size_t)h * NM * NDK + (size_t)(k0 + bk0) * NDK + d;
    bf16x8 bv;
#pragma unroll
    for (int q = 0; q < 8; ++q) bv[q] = f2bf(wp[q * NDK]);
    *(bf16x8*)&Bs[bcol][bk0] = bv;
    __syncthreads();

    bf16x8 af0 = *(bf16x8*)&As[wi * 32 + il][g4 * 8];
    bf16x8 af1 = *(bf16x8*)&As[wi * 32 + 16 + il][g4 * 8];
    bf16x8 bf0 = *(bf16x8*)&Bs[wc * 32 + il][g4 * 8];
    bf16x8 bf1 = *(bf16x8*)&Bs[wc * 32 + 16 + il][g4 * 8];
    acc[0][0] = __builtin_amdgcn_mfma_f32_16x16x32_bf16(af0, bf0, acc[0][0], 0, 0, 0);
    acc[0][1] = __builtin_amdgcn_mfma_f32_16x16x32_bf16(af0, bf1, acc[0][1], 0, 0, 0);
    acc[1][0] = __builtin_amdgcn_mfma_f32_16x16x32_bf16(af1, bf0, acc[1][0], 0, 0, 0);
    acc[1][1] = __builtin_amdgcn_mfma_f32_16x16x32_bf16(af1, bf1, acc[1][1], 0, 0, 0);
    __syncthreads();
  }

#pragma unroll
  for (int ih = 0; ih < 2; ++ih) {
#pragma unroll
    for (int dh = 0; dh < 2; ++dh) {
      int colhd = ct * 64 + wc * 32 + dh * 16 + il;
      int hh = colhd >> 5, dd = colhd & 31;
      float bias = pb[colhd];
      int r0 = rt * 64 + wi * 32 + ih * 16 + g4 * 4;
      int bb = r0 >> 10, ss = r0 & 1023;
      f32x4 c = acc[ih][dh];
      unsigned short ov[4];
#pragma unroll
      for (int e = 0; e < 4; ++e) ov[e] = f2bf(c[e] + bias);
      size_t idx = ((size_t)(bb * NH + hh) * NDK + dd) * NS + ss;
      *(bf16x4u*)(Pt + idx) = *(bf16x4u*)ov;
    }
  }
}

// ---------------------------------------------------------------------------
// s1/s2 PRE-SCALED by log2(e) so attn uses native exp2.
__global__ __launch_bounds__(256) void s_kernel(
    const unsigned short* __restrict__ Pt,
    const float* __restrict__ aw,   // 64 floats this layer
    const float* __restrict__ abp,  // attn_b + l
    float* __restrict__ s1o, float* __restrict__ s2o)
{
  const float LOG2E = 1.4426950408889634f;
  int t = blockIdx.x * 256 + threadIdx.x;   // (b*H+h)*S + s
  int bh = t >> 10, s = t & 1023;
  const unsigned short* p = Pt + (size_t)bh * NDK * NS + s;
  float s1 = 0.f, s2 = 0.f;
#pragma unroll
  for (int dd = 0; dd < NDK; ++dd) {
    float pv = bf2f(p[dd * NS]);
    s1 += pv * aw[dd];
    s2 += pv * aw[32 + dd];
  }
  s1o[t] = s1 * LOG2E;
  s2o[t] = (s2 + abp[0]) * LOG2E;
}

// ---------------------------------------------------------------------------
// Fused attention + residual + LayerNorm.
// Block = one (b, 32-row i-tile), 1024 threads = 16 waves.
// Wave w = (head = w&7, i-half = w>>3): 16 output rows x full j-range.
// Grid = B * (S/32) = 512 blocks -> 2 blocks/CU -> 32 waves/CU (100%).
// Softmax denominator via a 3rd MFMA with all-ones B (row sums in D-layout).
__global__ __launch_bounds__(1024) void attn_kernel(
    const float* __restrict__ xin,            // residual input (B,S,M) f32
    const unsigned short* __restrict__ Pt,    // (B,H,DK,S) bf16
    const float* __restrict__ s1a,            // (B,H,S), pre-scaled log2e
    const float* __restrict__ s2a,            // (B,H,S), pre-scaled, incl +ab
    const unsigned int* __restrict__ pkc,     // combined mask bits
    const unsigned int* __restrict__ pks,     // smask-only bits
    const int* __restrict__ typep,
    int layer,
    const float* __restrict__ lng,
    const float* __restrict__ lnb,
    float* __restrict__ xout)
{
  __shared__ float lds_c[32][260];   // concat tile, stride 260 (2-way max)

  int blk = blockIdx.x;
  int b = blk >> 5, it = blk & 31, i0 = it * 32;
  int t = threadIdx.x, w = t >> 6, lane = t & 63;
  int head = w & 7, ihalf = w >> 3;
  int il = lane & 15, g4 = lane >> 4;
  const unsigned char* pkb =
      (const unsigned char*)((typep[0] == 1 && layer > 0) ? pks : pkc);
  int irow = i0 + ihalf * 16 + il;                         // this lane's A-row
  size_t rowbase = ((size_t)(b * NS + irow) * NS) >> 3;    // mask byte index

  float s1v = s1a[(size_t)(b * NH + head) * NS + irow];

  bf16x8 ones;
#pragma unroll
  for (int e = 0; e < 8; ++e) ones[e] = (short)0x3F80;     // bf16 1.0

  f32x4 acc[2] = {};         // [dh]
  f32x4 acc_den = {};        // row-sum via ones-MFMA
  const unsigned short* ptb = Pt + (size_t)(b * NH + head) * NDK * NS;
  const float* s2b = s2a + (size_t)(b * NH + head) * NS;

  for (int j0 = 0; j0 < NS; j0 += 32) {
    int jb = j0 + g4 * 8;
    unsigned int mb = pkb[rowbase + (jb >> 3)];
    f32x4 s2lo = *(const f32x4*)(s2b + jb);
    f32x4 s2hi = *(const f32x4*)(s2b + jb + 4);
    float s2v[8] = {s2lo[0], s2lo[1], s2lo[2], s2lo[3],
                    s2hi[0], s2hi[1], s2hi[2], s2hi[3]};
    bf16x8 bf0 = *(const bf16x8*)(ptb + (size_t)il * NS + jb);
    bf16x8 bf1 = *(const bf16x8*)(ptb + (size_t)(16 + il) * NS + jb);
    float wv[8];
#pragma unroll
    for (int e = 0; e < 8; ++e) {
      float sc = s1v + s2v[e];
      sc = fmaxf(sc, 0.2f * sc);               // LeakyReLU(0.2) (scale>0 commutes)
      float ex = EXP2F(sc);                    // scores pre-scaled by log2e
      wv[e] = (mb & (1u << e)) ? 0.f : ex;
    }
    bf16x8 af;
#pragma unroll
    for (int e = 0; e < 8; ++e)
      af[e] = (short)__bfloat16_as_ushort(__float2bfloat16(wv[e]));
    acc[0] = __builtin_amdgcn_mfma_f32_16x16x32_bf16(af, bf0, acc[0], 0, 0, 0);
    acc[1] = __builtin_amdgcn_mfma_f32_16x16x32_bf16(af, bf1, acc[1], 0, 0, 0);
    acc_den = __builtin_amdgcn_mfma_f32_16x16x32_bf16(af, ones, acc_den, 0, 0, 0);
  }

  // normalize + scatter concat tile to LDS (D layout: col=il, row=g4*4+e)
  {
    f32x4 rd;
#pragma unroll
    for (int e = 0; e < 4; ++e) rd[e] = __builtin_amdgcn_rcpf(acc_den[e]);
#pragma unroll
    for (int dh = 0; dh < 2; ++dh) {
      f32x4 c = acc[dh];
      int colc = head * 32 + dh * 16 + il;
#pragma unroll
      for (int e = 0; e < 4; ++e)
        lds_c[ihalf * 16 + g4 * 4 + e][colc] = c[e] * rd[e];
    }
  }
  __syncthreads();

  // residual + LayerNorm: wave w handles rows w*2 .. w*2+1
#pragma unroll
  for (int rr = 0; rr < 2; ++rr) {
    int row = w * 2 + rr;
    f32x4 cv = *(f32x4*)&lds_c[row][lane * 4];
    const float* xp = xin + (size_t)(b * NS + i0 + row) * NM + lane * 4;
    f32x4 xv = *(const f32x4*)xp;
    f32x4 r;
#pragma unroll
    for (int e = 0; e < 4; ++e) r[e] = cv[e] + xv[e];
    float sm = r[0] + r[1] + r[2] + r[3];
    float sq = r[0] * r[0] + r[1] * r[1] + r[2] * r[2] + r[3] * r[3];
#pragma unroll
    for (int off = 32; off >= 1; off >>= 1) {
      sm += __shfl_xor(sm, off, 64);
      sq += __shfl_xor(sq, off, 64);
    }
    float mu = sm * (1.f / 256.f);
    float var = sq * (1.f / 256.f) - mu * mu;
    float inv = rsqrtf(var + 1e-5f);
    f32x4 gv = *(const f32x4*)(lng + lane * 4);
    f32x4 bv = *(const f32x4*)(lnb + lane * 4);
    f32x4 o;
#pragma unroll
    for (int e = 0; e < 4; ++e) o[e] = (r[e] - mu) * inv * gv[e] + bv[e];
    *(f32x4*)(xout + (size_t)(b * NS + i0 + row) * NM + lane * 4) = o;
  }
}

// ---------------------------------------------------------------------------
extern "C" void kernel_launch(void* const* d_in, const int* in_sizes, int n_in,
                              void* d_out, int out_size, void* d_ws, size_t ws_size,
                              hipStream_t stream)
{
  const int* adj = (const int*)d_in[0];
  const float* inputs = (const float*)d_in[1];
  const int* smask = (const int*)d_in[2];
  const int* typep = (const int*)d_in[3];
  const float* proj_w = (const float*)d_in[4];
  const float* proj_b = (const float*)d_in[5];
  const float* attn_w = (const float*)d_in[6];
  const float* attn_b = (const float*)d_in[7];
  const float* ln_g = (const float*)d_in[8];
  const float* ln_b = (const float*)d_in[9];
  float* out = (float*)d_out;

  char* ws = (char*)d_ws;
  unsigned int* pkc = (unsigned int*)(ws);                      // 2 MB
  unsigned int* pks = (unsigned int*)(ws + (2u << 20));         // 2 MB
  unsigned short* Pt = (unsigned short*)(ws + (4u << 20));      // 8 MB
  float* s1 = (float*)(ws + (12u << 20));                       // 512 KB
  float* s2 = (float*)(ws + (12u << 20) + (1u << 19));          // 512 KB
  float* x1 = (float*)(ws + (13u << 20));                       // 16 MB

  maskpack_kernel<<<2048, 256, 0, stream>>>(adj, smask, pkc, pks);

  for (int l = 0; l < NL; ++l) {
    const float* xin = (l == 0) ? inputs : x1;
    float* xout = (l == NL - 1) ? out : x1;
    proj_kernel<<<dim3(4, 256), 256, 0, stream>>>(
        xin, proj_w + (size_t)l * NH * NM * NDK, proj_b + (size_t)l * NH * NDK, Pt);
    s_kernel<<<512, 256, 0, stream>>>(Pt, attn_w + l * 64, attn_b + l, s1, s2);
    attn_kernel<<<512, 1024, 0, stream>>>(
        xin, Pt, s1, s2, pkc, pks, typep, l, ln_g + l * NM, ln_b + l * NM, xout);
  }
}

// Round 6
// 199.552 us; speedup vs baseline: 1.3540x; 1.3540x over previous
//
#include <hip/hip_runtime.h>
#include <hip/hip_bf16.h>
#include <math.h>

#define NB 16
#define NS 1024
#define NM 256
#define NH 8
#define NDK 32
#define NL 2

typedef __attribute__((ext_vector_type(4))) float f32x4;
typedef __attribute__((ext_vector_type(8))) short bf16x8;
typedef __attribute__((ext_vector_type(4))) short bf16x4u;

#if __has_builtin(__builtin_amdgcn_exp2f)
#define EXP2F(x) __builtin_amdgcn_exp2f(x)
#else
#define EXP2F(x) exp2f(x)
#endif

__device__ __forceinline__ unsigned short f2bf(float f) {
  unsigned int u = __builtin_bit_cast(unsigned int, f);
  unsigned int r = u + 0x7fffu + ((u >> 16) & 1u);
  return (unsigned short)(r >> 16);
}
__device__ __forceinline__ float bf2f(unsigned short h) {
  unsigned int u = ((unsigned int)h) << 16;
  return __builtin_bit_cast(float, u);
}

// ---------------------------------------------------------------------------
// Pack (smask || adj==0) and (smask) into bitmasks, 1 bit per (b,i,j).
__global__ __launch_bounds__(256) void maskpack_kernel(
    const int* __restrict__ adj, const int* __restrict__ sm,
    unsigned int* __restrict__ pkc, unsigned int* __restrict__ pks)
{
  int t = blockIdx.x * 256 + threadIdx.x;
  long base = (long)t * 32;
  const int4* a4 = (const int4*)(adj + base);
  const int4* m4 = (const int4*)(sm + base);
  union { int4 v[8]; int b[32]; } au, mu;
#pragma unroll
  for (int q = 0; q < 8; ++q) { au.v[q] = a4[q]; mu.v[q] = m4[q]; }
  unsigned int wc = 0, wsb = 0;
#pragma unroll
  for (int e = 0; e < 32; ++e) {
    unsigned int msk = mu.b[e] ? 1u : 0u;
    unsigned int cmb = (mu.b[e] || au.b[e] == 0) ? 1u : 0u;
    wsb |= msk << e;
    wc  |= cmb << e;
  }
  pkc[t] = wc; pks[t] = wsb;
}

// ---------------------------------------------------------------------------
// Projection GEMM -> Pt[b][h][d][s] (bf16), 64x64 tile, 4 waves.
__global__ __launch_bounds__(256) void proj_kernel(
    const float* __restrict__ x,        // (B*S, M)
    const float* __restrict__ pw,       // (H, M, DK) this layer
    const float* __restrict__ pb,       // (H*DK)
    unsigned short* __restrict__ Pt)    // (B,H,DK,S)
{
  __shared__ unsigned short As[64][40];
  __shared__ unsigned short Bs[64][40];

  int ct = blockIdx.x;
  int rt = blockIdx.y;
  int t = threadIdx.x;
  int w = t >> 6, lane = t & 63;
  int il = lane & 15, g4 = lane >> 4;
  int wi = w >> 1, wc = w & 1;

  f32x4 acc[2][2] = {};

  int arow = t >> 2, akoff = (t & 3) * 8;
  int bcol = t & 63, bk0 = (t >> 6) * 8;
  int hd = ct * 64 + bcol;
  int h = hd >> 5, d = hd & 31;

  for (int k0 = 0; k0 < NM; k0 += 32) {
    const float* xp = x + (size_t)(rt * 64 + arow) * NM + k0 + akoff;
    f32x4 v0 = *(const f32x4*)xp;
    f32x4 v1 = *(const f32x4*)(xp + 4);
    bf16x8 av;
    av[0] = f2bf(v0[0]); av[1] = f2bf(v0[1]); av[2] = f2bf(v0[2]); av[3] = f2bf(v0[3]);
    av[4] = f2bf(v1[0]); av[5] = f2bf(v1[1]); av[6] = f2bf(v1[2]); av[7] = f2bf(v1[3]);
    *(bf16x8*)&As[arow][akoff] = av;
    const float* wp = pw + (size_t)h * NM * NDK + (size_t)(k0 + bk0) * NDK + d;
    bf16x8 bv;
#pragma unroll
    for (int q = 0; q < 8; ++q) bv[q] = f2bf(wp[q * NDK]);
    *(bf16x8*)&Bs[bcol][bk0] = bv;
    __syncthreads();

    bf16x8 af0 = *(bf16x8*)&As[wi * 32 + il][g4 * 8];
    bf16x8 af1 = *(bf16x8*)&As[wi * 32 + 16 + il][g4 * 8];
    bf16x8 bf0 = *(bf16x8*)&Bs[wc * 32 + il][g4 * 8];
    bf16x8 bf1 = *(bf16x8*)&Bs[wc * 32 + 16 + il][g4 * 8];
    acc[0][0] = __builtin_amdgcn_mfma_f32_16x16x32_bf16(af0, bf0, acc[0][0], 0, 0, 0);
    acc[0][1] = __builtin_amdgcn_mfma_f32_16x16x32_bf16(af0, bf1, acc[0][1], 0, 0, 0);
    acc[1][0] = __builtin_amdgcn_mfma_f32_16x16x32_bf16(af1, bf0, acc[1][0], 0, 0, 0);
    acc[1][1] = __builtin_amdgcn_mfma_f32_16x16x32_bf16(af1, bf1, acc[1][1], 0, 0, 0);
    __syncthreads();
  }

#pragma unroll
  for (int ih = 0; ih < 2; ++ih) {
#pragma unroll
    for (int dh = 0; dh < 2; ++dh) {
      int colhd = ct * 64 + wc * 32 + dh * 16 + il;
      int hh = colhd >> 5, dd = colhd & 31;
      float bias = pb[colhd];
      int r0 = rt * 64 + wi * 32 + ih * 16 + g4 * 4;
      int bb = r0 >> 10, ss = r0 & 1023;
      f32x4 c = acc[ih][dh];
      unsigned short ov[4];
#pragma unroll
      for (int e = 0; e < 4; ++e) ov[e] = f2bf(c[e] + bias);
      size_t idx = ((size_t)(bb * NH + hh) * NDK + dd) * NS + ss;
      *(bf16x4u*)(Pt + idx) = *(bf16x4u*)ov;
    }
  }
}

// ---------------------------------------------------------------------------
// s1/s2 PRE-SCALED by log2(e) so attn uses native exp2.
__global__ __launch_bounds__(256) void s_kernel(
    const unsigned short* __restrict__ Pt,
    const float* __restrict__ aw,   // 64 floats this layer
    const float* __restrict__ abp,  // attn_b + l
    float* __restrict__ s1o, float* __restrict__ s2o)
{
  const float LOG2E = 1.4426950408889634f;
  int t = blockIdx.x * 256 + threadIdx.x;   // (b*H+h)*S + s
  int bh = t >> 10, s = t & 1023;
  const unsigned short* p = Pt + (size_t)bh * NDK * NS + s;
  float s1 = 0.f, s2 = 0.f;
#pragma unroll
  for (int dd = 0; dd < NDK; ++dd) {
    float pv = bf2f(p[dd * NS]);
    s1 += pv * aw[dd];
    s2 += pv * aw[32 + dd];
  }
  s1o[t] = s1 * LOG2E;
  s2o[t] = (s2 + abp[0]) * LOG2E;
}

// ---------------------------------------------------------------------------
// Fused attention + residual + LayerNorm (round-4 structure + SW pipeline +
// LDS mask-expansion table).
// Block = one (b, 32-row i-tile), 512 threads = 8 waves; wave w owns head w.
// Grid = B * (S/32) = 512 blocks -> 2 blocks/CU -> 16 waves/CU.
// Softmax denominator via a 3rd MFMA with all-ones B (row sums in D-layout).
__global__ __launch_bounds__(512) void attn_kernel(
    const float* __restrict__ xin,            // residual input (B,S,M) f32
    const unsigned short* __restrict__ Pt,    // (B,H,DK,S) bf16
    const float* __restrict__ s1a,            // (B,H,S), pre-scaled log2e
    const float* __restrict__ s2a,            // (B,H,S), pre-scaled, incl +ab
    const unsigned int* __restrict__ pkc,     // combined mask bits
    const unsigned int* __restrict__ pks,     // smask-only bits
    const int* __restrict__ typep,
    int layer,
    const float* __restrict__ lng,
    const float* __restrict__ lnb,
    float* __restrict__ xout)
{
  __shared__ float lds_c[32][260];   // concat tile, stride 260 (2-way max)
  __shared__ uint4 mtab[256];        // mask byte -> bf16x8 AND-mask (4 KB)

  int blk = blockIdx.x;
  int b = blk >> 5, it = blk & 31, i0 = it * 32;
  int t = threadIdx.x, w = t >> 6, lane = t & 63;   // w = head
  int il = lane & 15, g4 = lane >> 4;

  // Build mask-expansion table: bit e set -> halfword e zeroed.
  if (t < 256) {
    unsigned int m = t;
    uint4 e;
    e.x = ((m & 1u)   ? 0u : 0xFFFFu) | ((m & 2u)   ? 0u : 0xFFFF0000u);
    e.y = ((m & 4u)   ? 0u : 0xFFFFu) | ((m & 8u)   ? 0u : 0xFFFF0000u);
    e.z = ((m & 16u)  ? 0u : 0xFFFFu) | ((m & 32u)  ? 0u : 0xFFFF0000u);
    e.w = ((m & 64u)  ? 0u : 0xFFFFu) | ((m & 128u) ? 0u : 0xFFFF0000u);
    mtab[t] = e;
  }
  __syncthreads();

  const unsigned char* pkb =
      (const unsigned char*)((typep[0] == 1 && layer > 0) ? pks : pkc);
  size_t rowbase0 = ((size_t)(b * NS + i0 + il) * NS) >> 3;       // byte idx
  size_t rowbase1 = ((size_t)(b * NS + i0 + 16 + il) * NS) >> 3;

  float s1v[2];
#pragma unroll
  for (int ih = 0; ih < 2; ++ih)
    s1v[ih] = s1a[(size_t)(b * NH + w) * NS + i0 + ih * 16 + il];

  bf16x8 ones;
#pragma unroll
  for (int e = 0; e < 8; ++e) ones[e] = (short)0x3F80;   // bf16 1.0

  f32x4 acc[2][2] = {};      // [ih][dh]
  f32x4 acc_den[2] = {};     // [ih] row-sum via ones-MFMA
  const unsigned short* ptb = Pt + (size_t)(b * NH + w) * NDK * NS;
  const float* s2b = s2a + (size_t)(b * NH + w) * NS;
  const int joff = g4 * 8;

  auto loadj = [&](int j, unsigned int& m0, unsigned int& m1,
                   f32x4& sL, f32x4& sH, bf16x8& b0, bf16x8& b1) {
    int jb = j + joff;
    m0 = pkb[rowbase0 + (jb >> 3)];
    m1 = pkb[rowbase1 + (jb >> 3)];
    sL = *(const f32x4*)(s2b + jb);
    sH = *(const f32x4*)(s2b + jb + 4);
    b0 = *(const bf16x8*)(ptb + (size_t)il * NS + jb);
    b1 = *(const bf16x8*)(ptb + (size_t)(16 + il) * NS + jb);
  };

  auto step = [&](unsigned int m0, unsigned int m1, f32x4 sL, f32x4 sH,
                  bf16x8 b0, bf16x8 b1) {
    float s2v[8] = {sL[0], sL[1], sL[2], sL[3], sH[0], sH[1], sH[2], sH[3]};
#pragma unroll
    for (int ih = 0; ih < 2; ++ih) {
      unsigned int mb = ih ? m1 : m0;
      float s1s = s1v[ih];
      bf16x8 af;
#pragma unroll
      for (int e = 0; e < 8; ++e) {
        float sc = s1s + s2v[e];
        sc = fmaxf(sc, 0.2f * sc);             // LeakyReLU(0.2), scale>0 commutes
        af[e] = (short)__bfloat16_as_ushort(__float2bfloat16(EXP2F(sc)));
      }
      uint4 mk = mtab[mb];
      uint4 au = __builtin_bit_cast(uint4, af);
      au.x &= mk.x; au.y &= mk.y; au.z &= mk.z; au.w &= mk.w;
      af = __builtin_bit_cast(bf16x8, au);
      acc[ih][0] = __builtin_amdgcn_mfma_f32_16x16x32_bf16(af, b0, acc[ih][0], 0, 0, 0);
      acc[ih][1] = __builtin_amdgcn_mfma_f32_16x16x32_bf16(af, b1, acc[ih][1], 0, 0, 0);
      acc_den[ih] = __builtin_amdgcn_mfma_f32_16x16x32_bf16(af, ones, acc_den[ih], 0, 0, 0);
    }
  };

  unsigned int m0A, m1A, m0B, m1B;
  f32x4 sLA, sHA, sLB, sHB;
  bf16x8 b0A, b1A, b0B, b1B;

  loadj(0, m0A, m1A, sLA, sHA, b0A, b1A);
  for (int j0 = 0; j0 < NS; j0 += 64) {
    loadj(j0 + 32, m0B, m1B, sLB, sHB, b0B, b1B);
    step(m0A, m1A, sLA, sHA, b0A, b1A);
    int jn = (j0 + 64 < NS) ? (j0 + 64) : 0;   // wrap: harmless extra prefetch
    loadj(jn, m0A, m1A, sLA, sHA, b0A, b1A);
    step(m0B, m1B, sLB, sHB, b0B, b1B);
  }

  // normalize + scatter concat tile to LDS (D layout: col=il, row=g4*4+e)
#pragma unroll
  for (int ih = 0; ih < 2; ++ih) {
    f32x4 rd;
#pragma unroll
    for (int e = 0; e < 4; ++e) rd[e] = __builtin_amdgcn_rcpf(acc_den[ih][e]);
#pragma unroll
    for (int dh = 0; dh < 2; ++dh) {
      f32x4 c = acc[ih][dh];
      int colc = w * 32 + dh * 16 + il;
#pragma unroll
      for (int e = 0; e < 4; ++e)
        lds_c[ih * 16 + g4 * 4 + e][colc] = c[e] * rd[e];
    }
  }
  __syncthreads();

  // residual + LayerNorm: wave w handles rows w*4 .. w*4+3
#pragma unroll
  for (int rr = 0; rr < 4; ++rr) {
    int row = w * 4 + rr;
    f32x4 cv = *(f32x4*)&lds_c[row][lane * 4];
    const float* xp = xin + (size_t)(b * NS + i0 + row) * NM + lane * 4;
    f32x4 xv = *(const f32x4*)xp;
    f32x4 r;
#pragma unroll
    for (int e = 0; e < 4; ++e) r[e] = cv[e] + xv[e];
    float sm = r[0] + r[1] + r[2] + r[3];
    float sq = r[0] * r[0] + r[1] * r[1] + r[2] * r[2] + r[3] * r[3];
#pragma unroll
    for (int off = 32; off >= 1; off >>= 1) {
      sm += __shfl_xor(sm, off, 64);
      sq += __shfl_xor(sq, off, 64);
    }
    float mu = sm * (1.f / 256.f);
    float var = sq * (1.f / 256.f) - mu * mu;
    float inv = rsqrtf(var + 1e-5f);
    f32x4 gv = *(const f32x4*)(lng + lane * 4);
    f32x4 bv = *(const f32x4*)(lnb + lane * 4);
    f32x4 o;
#pragma unroll
    for (int e = 0; e < 4; ++e) o[e] = (r[e] - mu) * inv * gv[e] + bv[e];
    *(f32x4*)(xout + (size_t)(b * NS + i0 + row) * NM + lane * 4) = o;
  }
}

// ---------------------------------------------------------------------------
extern "C" void kernel_launch(void* const* d_in, const int* in_sizes, int n_in,
                              void* d_out, int out_size, void* d_ws, size_t ws_size,
                              hipStream_t stream)
{
  const int* adj = (const int*)d_in[0];
  const float* inputs = (const float*)d_in[1];
  const int* smask = (const int*)d_in[2];
  const int* typep = (const int*)d_in[3];
  const float* proj_w = (const float*)d_in[4];
  const float* proj_b = (const float*)d_in[5];
  const float* attn_w = (const float*)d_in[6];
  const float* attn_b = (const float*)d_in[7];
  const float* ln_g = (const float*)d_in[8];
  const float* ln_b = (const float*)d_in[9];
  float* out = (float*)d_out;

  char* ws = (char*)d_ws;
  unsigned int* pkc = (unsigned int*)(ws);                      // 2 MB
  unsigned int* pks = (unsigned int*)(ws + (2u << 20));         // 2 MB
  unsigned short* Pt = (unsigned short*)(ws + (4u << 20));      // 8 MB
  float* s1 = (float*)(ws + (12u << 20));                       // 512 KB
  float* s2 = (float*)(ws + (12u << 20) + (1u << 19));          // 512 KB
  float* x1 = (float*)(ws + (13u << 20));                       // 16 MB

  maskpack_kernel<<<2048, 256, 0, stream>>>(adj, smask, pkc, pks);

  for (int l = 0; l < NL; ++l) {
    const float* xin = (l == 0) ? inputs : x1;
    float* xout = (l == NL - 1) ? out : x1;
    proj_kernel<<<dim3(4, 256), 256, 0, stream>>>(
        xin, proj_w + (size_t)l * NH * NM * NDK, proj_b + (size_t)l * NH * NDK, Pt);
    s_kernel<<<512, 256, 0, stream>>>(Pt, attn_w + l * 64, attn_b + l, s1, s2);
    attn_kernel<<<512, 512, 0, stream>>>(
        xin, Pt, s1, s2, pkc, pks, typep, l, ln_g + l * NM, ln_b + l * NM, xout);
  }
}

// Round 7
// 165.393 us; speedup vs baseline: 1.6337x; 1.2065x over previous
//
#include <hip/hip_runtime.h>
#include <hip/hip_bf16.h>
#include <math.h>

#define NB 16
#define NS 1024
#define NM 256
#define NH 8
#define NDK 32
#define NL 2

typedef __attribute__((ext_vector_type(4))) float f32x4;
typedef __attribute__((ext_vector_type(8))) short bf16x8;
typedef __attribute__((ext_vector_type(4))) short bf16x4u;

#if __has_builtin(__builtin_amdgcn_exp2f)
#define EXP2F(x) __builtin_amdgcn_exp2f(x)
#else
#define EXP2F(x) exp2f(x)
#endif

__device__ __forceinline__ unsigned short f2bf(float f) {
  unsigned int u = __builtin_bit_cast(unsigned int, f);
  unsigned int r = u + 0x7fffu + ((u >> 16) & 1u);
  return (unsigned short)(r >> 16);
}
__device__ __forceinline__ float bf2f(unsigned short h) {
  unsigned int u = ((unsigned int)h) << 16;
  return __builtin_bit_cast(float, u);
}

// ---------------------------------------------------------------------------
// Pack (smask || adj==0) and (smask) into bitmasks, 1 bit per (b,i,j).
__global__ __launch_bounds__(256) void maskpack_kernel(
    const int* __restrict__ adj, const int* __restrict__ sm,
    unsigned int* __restrict__ pkc, unsigned int* __restrict__ pks)
{
  int t = blockIdx.x * 256 + threadIdx.x;
  long base = (long)t * 32;
  const int4* a4 = (const int4*)(adj + base);
  const int4* m4 = (const int4*)(sm + base);
  union { int4 v[8]; int b[32]; } au, mu;
#pragma unroll
  for (int q = 0; q < 8; ++q) { au.v[q] = a4[q]; mu.v[q] = m4[q]; }
  unsigned int wc = 0, wsb = 0;
#pragma unroll
  for (int e = 0; e < 32; ++e) {
    unsigned int msk = mu.b[e] ? 1u : 0u;
    unsigned int cmb = (mu.b[e] || au.b[e] == 0) ? 1u : 0u;
    wsb |= msk << e;
    wc  |= cmb << e;
  }
  pkc[t] = wc; pks[t] = wsb;
}

// ---------------------------------------------------------------------------
// Projection GEMM -> Pt[b][h][d][s] (bf16), 64x64 tile, 4 waves.
__global__ __launch_bounds__(256) void proj_kernel(
    const float* __restrict__ x,        // (B*S, M)
    const float* __restrict__ pw,       // (H, M, DK) this layer
    const float* __restrict__ pb,       // (H*DK)
    unsigned short* __restrict__ Pt)    // (B,H,DK,S)
{
  __shared__ unsigned short As[64][40];
  __shared__ unsigned short Bs[64][40];

  int ct = blockIdx.x;
  int rt = blockIdx.y;
  int t = threadIdx.x;
  int w = t >> 6, lane = t & 63;
  int il = lane & 15, g4 = lane >> 4;
  int wi = w >> 1, wc = w & 1;

  f32x4 acc[2][2] = {};

  int arow = t >> 2, akoff = (t & 3) * 8;
  int bcol = t & 63, bk0 = (t >> 6) * 8;
  int hd = ct * 64 + bcol;
  int h = hd >> 5, d = hd & 31;

  for (int k0 = 0; k0 < NM; k0 += 32) {
    const float* xp = x + (size_t)(rt * 64 + arow) * NM + k0 + akoff;
    f32x4 v0 = *(const f32x4*)xp;
    f32x4 v1 = *(const f32x4*)(xp + 4);
    bf16x8 av;
    av[0] = f2bf(v0[0]); av[1] = f2bf(v0[1]); av[2] = f2bf(v0[2]); av[3] = f2bf(v0[3]);
    av[4] = f2bf(v1[0]); av[5] = f2bf(v1[1]); av[6] = f2bf(v1[2]); av[7] = f2bf(v1[3]);
    *(bf16x8*)&As[arow][akoff] = av;
    const float* wp = pw + (size_t)h * NM * NDK + (size_t)(k0 + bk0) * NDK + d;
    bf16x8 bv;
#pragma unroll
    for (int q = 0; q < 8; ++q) bv[q] = f2bf(wp[q * NDK]);
    *(bf16x8*)&Bs[bcol][bk0] = bv;
    __syncthreads();

    bf16x8 af0 = *(bf16x8*)&As[wi * 32 + il][g4 * 8];
    bf16x8 af1 = *(bf16x8*)&As[wi * 32 + 16 + il][g4 * 8];
    bf16x8 bf0 = *(bf16x8*)&Bs[wc * 32 + il][g4 * 8];
    bf16x8 bf1 = *(bf16x8*)&Bs[wc * 32 + 16 + il][g4 * 8];
    acc[0][0] = __builtin_amdgcn_mfma_f32_16x16x32_bf16(af0, bf0, acc[0][0], 0, 0, 0);
    acc[0][1] = __builtin_amdgcn_mfma_f32_16x16x32_bf16(af0, bf1, acc[0][1], 0, 0, 0);
    acc[1][0] = __builtin_amdgcn_mfma_f32_16x16x32_bf16(af1, bf0, acc[1][0], 0, 0, 0);
    acc[1][1] = __builtin_amdgcn_mfma_f32_16x16x32_bf16(af1, bf1, acc[1][1], 0, 0, 0);
    __syncthreads();
  }

#pragma unroll
  for (int ih = 0; ih < 2; ++ih) {
#pragma unroll
    for (int dh = 0; dh < 2; ++dh) {
      int colhd = ct * 64 + wc * 32 + dh * 16 + il;
      int hh = colhd >> 5, dd = colhd & 31;
      float bias = pb[colhd];
      int r0 = rt * 64 + wi * 32 + ih * 16 + g4 * 4;
      int bb = r0 >> 10, ss = r0 & 1023;
      f32x4 c = acc[ih][dh];
      unsigned short ov[4];
#pragma unroll
      for (int e = 0; e < 4; ++e) ov[e] = f2bf(c[e] + bias);
      size_t idx = ((size_t)(bb * NH + hh) * NDK + dd) * NS + ss;
      *(bf16x4u*)(Pt + idx) = *(bf16x4u*)ov;
    }
  }
}

// ---------------------------------------------------------------------------
// s1/s2 PRE-SCALED by log2(e) so attn uses native exp2.
__global__ __launch_bounds__(256) void s_kernel(
    const unsigned short* __restrict__ Pt,
    const float* __restrict__ aw,   // 64 floats this layer
    const float* __restrict__ abp,  // attn_b + l
    float* __restrict__ s1o, float* __restrict__ s2o)
{
  const float LOG2E = 1.4426950408889634f;
  int t = blockIdx.x * 256 + threadIdx.x;   // (b*H+h)*S + s
  int bh = t >> 10, s = t & 1023;
  const unsigned short* p = Pt + (size_t)bh * NDK * NS + s;
  float s1 = 0.f, s2 = 0.f;
#pragma unroll
  for (int dd = 0; dd < NDK; ++dd) {
    float pv = bf2f(p[dd * NS]);
    s1 += pv * aw[dd];
    s2 += pv * aw[32 + dd];
  }
  s1o[t] = s1 * LOG2E;
  s2o[t] = (s2 + abp[0]) * LOG2E;
}

// ---------------------------------------------------------------------------
// Attention with LDS-staged Pt.
// Block = (b, head, i-quarter): 512 threads = 8 waves; wave w owns 16 i-rows
// per pass (2 passes = 256 rows). Pt head-slab staged in two 32KB j-halves,
// XOR-swizzled (byte ^= (row&7)<<4) for conflict-free ds_read_b128.
// j-loop: LDS + VALU only, except one uint4 mask load per row per 4 j-steps.
// Output: normalized PV concat written f32 to co (B,S,M) — LN is separate.
__global__ __launch_bounds__(512) void attn_kernel(
    const unsigned short* __restrict__ Pt,    // (B,H,DK,S) bf16
    const float* __restrict__ s1a,            // (B,H,S), pre-scaled log2e
    const float* __restrict__ s2a,            // (B,H,S), pre-scaled, incl +ab
    const unsigned int* __restrict__ pkc,     // combined mask bits
    const unsigned int* __restrict__ pks,     // smask-only bits
    const int* __restrict__ typep,
    int layer,
    float* __restrict__ co)                   // (B,S,M) f32 concat out
{
  __shared__ __align__(16) unsigned short ptl[32 * 512];  // 32KB, swizzled
  __shared__ float s2l[512];                              // 2KB

  // XCD chunk swizzle: 64 consecutive logical blocks (2 batches) per XCD.
  int orig = blockIdx.x;
  int lb = (orig & 7) * 64 + (orig >> 3);
  int iq = lb & 3, bh = lb >> 2;
  int b = bh >> 3, h = bh & 7;

  int t = threadIdx.x, w = t >> 6, lane = t & 63;
  int il = lane & 15, g4 = lane >> 4;
  int xorv = (il & 7) << 4;

  const unsigned char* pkb =
      (const unsigned char*)((typep[0] == 1 && layer > 0) ? pks : pkc);
  const unsigned short* ptg = Pt + (size_t)bh * NDK * NS;
  const float* s2b = s2a + (size_t)bh * NS;

  bf16x8 ones;
#pragma unroll
  for (int e = 0; e < 8; ++e) ones[e] = (short)0x3F80;     // bf16 1.0

  float s1v[2];
  const unsigned char* mrow[2];
#pragma unroll
  for (int p = 0; p < 2; ++p) {
    int rbase = iq * 256 + p * 128 + w * 16;
    s1v[p] = s1a[(size_t)bh * NS + rbase + il];
    mrow[p] = pkb + (((size_t)(b * NS + rbase + il) * NS) >> 3);
  }

  f32x4 acc0[2] = {}, acc1[2] = {}, accd[2] = {};

  for (int jh = 0; jh < 2; ++jh) {
    __syncthreads();
    // stage Pt half-slab (32 rows x 512 cols bf16 = 32KB), swizzled
    {
      const char* srcb = (const char*)ptg;
#pragma unroll
      for (int q = 0; q < 4; ++q) {
        int pos = q * 8192 + t * 16;          // 0..32767
        int r = pos >> 10;                    // row 0..31
        int incol = pos & 1023;               // byte within half-row
        uint4 v = *(const uint4*)(srcb + r * 2048 + jh * 1024 + incol);
        *(uint4*)((char*)ptl + r * 1024 + (incol ^ ((r & 7) << 4))) = v;
      }
      if (t < 128)
        ((f32x4*)s2l)[t] = *(const f32x4*)(s2b + jh * 512 + t * 4);
    }
    __syncthreads();

#pragma unroll
    for (int p = 0; p < 2; ++p) {
      for (int jg = jh * 512; jg < jh * 512 + 512; jg += 128) {
        uint4 mk = *(const uint4*)(mrow[p] + (jg >> 3));   // 128 j-bits
#pragma unroll
        for (int s = 0; s < 4; ++s) {
          int j0 = jg + s * 32;
          unsigned int mword = (&mk.x)[s];
          unsigned int mb = (mword >> (g4 * 8)) & 0xFFu;
          int jl = j0 - jh * 512 + g4 * 8;                 // local col
          int coff = (jl * 2) ^ xorv;
          const char* prow = (const char*)ptl + il * 1024;
          bf16x8 b0 = *(const bf16x8*)(prow + coff);
          bf16x8 b1 = *(const bf16x8*)(prow + 16 * 1024 + coff);
          f32x4 sL = *(const f32x4*)&s2l[jl];
          f32x4 sH = *(const f32x4*)&s2l[jl + 4];
          float s2v[8] = {sL[0], sL[1], sL[2], sL[3],
                          sH[0], sH[1], sH[2], sH[3]};
          bf16x8 af;
#pragma unroll
          for (int e = 0; e < 8; ++e) {
            float sc = s1v[p] + s2v[e];
            sc = fmaxf(sc, 0.2f * sc);         // LeakyReLU(0.2)
            float ex = EXP2F(sc);              // pre-scaled by log2e
            ex = (mb & (1u << e)) ? 0.f : ex;
            af[e] = (short)__bfloat16_as_ushort(__float2bfloat16(ex));
          }
          acc0[p] = __builtin_amdgcn_mfma_f32_16x16x32_bf16(af, b0, acc0[p], 0, 0, 0);
          acc1[p] = __builtin_amdgcn_mfma_f32_16x16x32_bf16(af, b1, acc1[p], 0, 0, 0);
          accd[p] = __builtin_amdgcn_mfma_f32_16x16x32_bf16(af, ones, accd[p], 0, 0, 0);
        }
      }
    }
  }

  // normalize + store concat (D layout: col=il, row=g4*4+e)
#pragma unroll
  for (int p = 0; p < 2; ++p) {
    int rbase = iq * 256 + p * 128 + w * 16;
    f32x4 rd;
#pragma unroll
    for (int e = 0; e < 4; ++e) rd[e] = __builtin_amdgcn_rcpf(accd[p][e]);
    float* cob = co + (size_t)(b * NS + rbase + g4 * 4) * NM + h * 32 + il;
#pragma unroll
    for (int e = 0; e < 4; ++e) {
      cob[(size_t)e * NM] = acc0[p][e] * rd[e];
      cob[(size_t)e * NM + 16] = acc1[p][e] * rd[e];
    }
  }
}

// ---------------------------------------------------------------------------
// Residual + LayerNorm: row r -> LN(xin[r] + co[r]) * g + b.
// One wave per row; in-place co==xout is safe (reads precede writes per wave).
__global__ __launch_bounds__(256) void ln_kernel(
    const float* __restrict__ xin, const float* __restrict__ co,
    const float* __restrict__ lng, const float* __restrict__ lnb,
    float* __restrict__ xout)
{
  int row = blockIdx.x * 4 + (threadIdx.x >> 6);
  int lane = threadIdx.x & 63;
  size_t base = (size_t)row * NM + lane * 4;
  f32x4 cv = *(const f32x4*)(co + base);
  f32x4 xv = *(const f32x4*)(xin + base);
  f32x4 r;
#pragma unroll
  for (int e = 0; e < 4; ++e) r[e] = cv[e] + xv[e];
  float sm = r[0] + r[1] + r[2] + r[3];
  float sq = r[0] * r[0] + r[1] * r[1] + r[2] * r[2] + r[3] * r[3];
#pragma unroll
  for (int off = 32; off >= 1; off >>= 1) {
    sm += __shfl_xor(sm, off, 64);
    sq += __shfl_xor(sq, off, 64);
  }
  float mu = sm * (1.f / 256.f);
  float var = sq * (1.f / 256.f) - mu * mu;
  float inv = rsqrtf(var + 1e-5f);
  f32x4 gv = *(const f32x4*)(lng + lane * 4);
  f32x4 bv = *(const f32x4*)(lnb + lane * 4);
  f32x4 o;
#pragma unroll
  for (int e = 0; e < 4; ++e) o[e] = (r[e] - mu) * inv * gv[e] + bv[e];
  *(f32x4*)(xout + base) = o;
}

// ---------------------------------------------------------------------------
extern "C" void kernel_launch(void* const* d_in, const int* in_sizes, int n_in,
                              void* d_out, int out_size, void* d_ws, size_t ws_size,
                              hipStream_t stream)
{
  const int* adj = (const int*)d_in[0];
  const float* inputs = (const float*)d_in[1];
  const int* smask = (const int*)d_in[2];
  const int* typep = (const int*)d_in[3];
  const float* proj_w = (const float*)d_in[4];
  const float* proj_b = (const float*)d_in[5];
  const float* attn_w = (const float*)d_in[6];
  const float* attn_b = (const float*)d_in[7];
  const float* ln_g = (const float*)d_in[8];
  const float* ln_b = (const float*)d_in[9];
  float* out = (float*)d_out;

  char* ws = (char*)d_ws;
  unsigned int* pkc = (unsigned int*)(ws);                      // 2 MB
  unsigned int* pks = (unsigned int*)(ws + (2u << 20));         // 2 MB
  unsigned short* Pt = (unsigned short*)(ws + (4u << 20));      // 8 MB
  float* s1 = (float*)(ws + (12u << 20));                       // 512 KB
  float* s2 = (float*)(ws + (12u << 20) + (1u << 19));          // 512 KB
  float* x1 = (float*)(ws + (13u << 20));                       // 16 MB
  float* co = out;   // d_out doubles as concat scratch (fully overwritten)

  maskpack_kernel<<<2048, 256, 0, stream>>>(adj, smask, pkc, pks);

  for (int l = 0; l < NL; ++l) {
    const float* xin = (l == 0) ? inputs : x1;
    float* xout = (l == NL - 1) ? out : x1;
    proj_kernel<<<dim3(4, 256), 256, 0, stream>>>(
        xin, proj_w + (size_t)l * NH * NM * NDK, proj_b + (size_t)l * NH * NDK, Pt);
    s_kernel<<<512, 256, 0, stream>>>(Pt, attn_w + l * 64, attn_b + l, s1, s2);
    attn_kernel<<<512, 512, 0, stream>>>(
        Pt, s1, s2, pkc, pks, typep, l, co);
    ln_kernel<<<4096, 256, 0, stream>>>(xin, co, ln_g + l * NM, ln_b + l * NM, xout);
  }
}

// Round 8
// 163.725 us; speedup vs baseline: 1.6503x; 1.0102x over previous
//
#include <hip/hip_runtime.h>
#include <hip/hip_bf16.h>
#include <math.h>

#define NB 16
#define NS 1024
#define NM 256
#define NH 8
#define NDK 32
#define NL 2

typedef __attribute__((ext_vector_type(4))) float f32x4;
typedef __attribute__((ext_vector_type(8))) short bf16x8;
typedef __attribute__((ext_vector_type(4))) short bf16x4u;

#if __has_builtin(__builtin_amdgcn_exp2f)
#define EXP2F(x) __builtin_amdgcn_exp2f(x)
#else
#define EXP2F(x) exp2f(x)
#endif

__device__ __forceinline__ unsigned short f2bf(float f) {
  unsigned int u = __builtin_bit_cast(unsigned int, f);
  unsigned int r = u + 0x7fffu + ((u >> 16) & 1u);
  return (unsigned short)(r >> 16);
}
__device__ __forceinline__ float bf2f(unsigned short h) {
  unsigned int u = ((unsigned int)h) << 16;
  return __builtin_bit_cast(float, u);
}

// ---------------------------------------------------------------------------
// Pack (smask || adj==0) and (smask) into bitmasks, 1 bit per (b,i,j).
__global__ __launch_bounds__(256) void maskpack_kernel(
    const int* __restrict__ adj, const int* __restrict__ sm,
    unsigned int* __restrict__ pkc, unsigned int* __restrict__ pks)
{
  int t = blockIdx.x * 256 + threadIdx.x;
  long base = (long)t * 32;
  const int4* a4 = (const int4*)(adj + base);
  const int4* m4 = (const int4*)(sm + base);
  union { int4 v[8]; int b[32]; } au, mu;
#pragma unroll
  for (int q = 0; q < 8; ++q) { au.v[q] = a4[q]; mu.v[q] = m4[q]; }
  unsigned int wc = 0, wsb = 0;
#pragma unroll
  for (int e = 0; e < 32; ++e) {
    unsigned int msk = mu.b[e] ? 1u : 0u;
    unsigned int cmb = (mu.b[e] || au.b[e] == 0) ? 1u : 0u;
    wsb |= msk << e;
    wc  |= cmb << e;
  }
  pkc[t] = wc; pks[t] = wsb;
}

// ---------------------------------------------------------------------------
// Projection GEMM -> Pt[b][h][d][s] (bf16), 64x64 tile, 4 waves.
__global__ __launch_bounds__(256) void proj_kernel(
    const float* __restrict__ x,        // (B*S, M)
    const float* __restrict__ pw,       // (H, M, DK) this layer
    const float* __restrict__ pb,       // (H*DK)
    unsigned short* __restrict__ Pt)    // (B,H,DK,S)
{
  __shared__ unsigned short As[64][40];
  __shared__ unsigned short Bs[64][40];

  int ct = blockIdx.x;
  int rt = blockIdx.y;
  int t = threadIdx.x;
  int w = t >> 6, lane = t & 63;
  int il = lane & 15, g4 = lane >> 4;
  int wi = w >> 1, wc = w & 1;

  f32x4 acc[2][2] = {};

  int arow = t >> 2, akoff = (t & 3) * 8;
  int bcol = t & 63, bk0 = (t >> 6) * 8;
  int hd = ct * 64 + bcol;
  int h = hd >> 5, d = hd & 31;

  for (int k0 = 0; k0 < NM; k0 += 32) {
    const float* xp = x + (size_t)(rt * 64 + arow) * NM + k0 + akoff;
    f32x4 v0 = *(const f32x4*)xp;
    f32x4 v1 = *(const f32x4*)(xp + 4);
    bf16x8 av;
    av[0] = f2bf(v0[0]); av[1] = f2bf(v0[1]); av[2] = f2bf(v0[2]); av[3] = f2bf(v0[3]);
    av[4] = f2bf(v1[0]); av[5] = f2bf(v1[1]); av[6] = f2bf(v1[2]); av[7] = f2bf(v1[3]);
    *(bf16x8*)&As[arow][akoff] = av;
    const float* wp = pw + (size_t)h * NM * NDK + (size_t)(k0 + bk0) * NDK + d;
    bf16x8 bv;
#pragma unroll
    for (int q = 0; q < 8; ++q) bv[q] = f2bf(wp[q * NDK]);
    *(bf16x8*)&Bs[bcol][bk0] = bv;
    __syncthreads();

    bf16x8 af0 = *(bf16x8*)&As[wi * 32 + il][g4 * 8];
    bf16x8 af1 = *(bf16x8*)&As[wi * 32 + 16 + il][g4 * 8];
    bf16x8 bf0 = *(bf16x8*)&Bs[wc * 32 + il][g4 * 8];
    bf16x8 bf1 = *(bf16x8*)&Bs[wc * 32 + 16 + il][g4 * 8];
    acc[0][0] = __builtin_amdgcn_mfma_f32_16x16x32_bf16(af0, bf0, acc[0][0], 0, 0, 0);
    acc[0][1] = __builtin_amdgcn_mfma_f32_16x16x32_bf16(af0, bf1, acc[0][1], 0, 0, 0);
    acc[1][0] = __builtin_amdgcn_mfma_f32_16x16x32_bf16(af1, bf0, acc[1][0], 0, 0, 0);
    acc[1][1] = __builtin_amdgcn_mfma_f32_16x16x32_bf16(af1, bf1, acc[1][1], 0, 0, 0);
    __syncthreads();
  }

#pragma unroll
  for (int ih = 0; ih < 2; ++ih) {
#pragma unroll
    for (int dh = 0; dh < 2; ++dh) {
      int colhd = ct * 64 + wc * 32 + dh * 16 + il;
      int hh = colhd >> 5, dd = colhd & 31;
      float bias = pb[colhd];
      int r0 = rt * 64 + wi * 32 + ih * 16 + g4 * 4;
      int bb = r0 >> 10, ss = r0 & 1023;
      f32x4 c = acc[ih][dh];
      unsigned short ov[4];
#pragma unroll
      for (int e = 0; e < 4; ++e) ov[e] = f2bf(c[e] + bias);
      size_t idx = ((size_t)(bb * NH + hh) * NDK + dd) * NS + ss;
      *(bf16x4u*)(Pt + idx) = *(bf16x4u*)ov;
    }
  }
}

// ---------------------------------------------------------------------------
// s1/s2 PRE-SCALED by log2(e) so attn uses native exp2.
__global__ __launch_bounds__(256) void s_kernel(
    const unsigned short* __restrict__ Pt,
    const float* __restrict__ aw,   // 64 floats this layer
    const float* __restrict__ abp,  // attn_b + l
    float* __restrict__ s1o, float* __restrict__ s2o)
{
  const float LOG2E = 1.4426950408889634f;
  int t = blockIdx.x * 256 + threadIdx.x;   // (b*H+h)*S + s
  int bh = t >> 10, s = t & 1023;
  const unsigned short* p = Pt + (size_t)bh * NDK * NS + s;
  float s1 = 0.f, s2 = 0.f;
#pragma unroll
  for (int dd = 0; dd < NDK; ++dd) {
    float pv = bf2f(p[dd * NS]);
    s1 += pv * aw[dd];
    s2 += pv * aw[32 + dd];
  }
  s1o[t] = s1 * LOG2E;
  s2o[t] = (s2 + abp[0]) * LOG2E;
}

// ---------------------------------------------------------------------------
// Attention with LDS-staged Pt — 16-wave blocks for 32 waves/CU.
// Block = (b, head, i-quarter): 1024 threads = 16 waves; wave w owns 16 rows
// (iq*256 + w*16). Pt head-slab staged in two 32KB j-halves, XOR-swizzled.
// Same per-block work/LDS as the 8-wave version; only occupancy doubles.
__global__ __launch_bounds__(1024, 8) void attn_kernel(
    const unsigned short* __restrict__ Pt,    // (B,H,DK,S) bf16
    const float* __restrict__ s1a,            // (B,H,S), pre-scaled log2e
    const float* __restrict__ s2a,            // (B,H,S), pre-scaled, incl +ab
    const unsigned int* __restrict__ pkc,     // combined mask bits
    const unsigned int* __restrict__ pks,     // smask-only bits
    const int* __restrict__ typep,
    int layer,
    float* __restrict__ co)                   // (B,S,M) f32 concat out
{
  __shared__ __align__(16) unsigned short ptl[32 * 512];  // 32KB, swizzled
  __shared__ float s2l[1024];                             // 4KB (both halves)

  // XCD chunk swizzle: 64 consecutive logical blocks (2 batches) per XCD.
  int orig = blockIdx.x;
  int lb = (orig & 7) * 64 + (orig >> 3);
  int iq = lb & 3, bh = lb >> 2;
  int b = bh >> 3, h = bh & 7;

  int t = threadIdx.x, w = t >> 6, lane = t & 63;
  int il = lane & 15, g4 = lane >> 4;
  int xorv = (il & 7) << 4;

  const unsigned char* pkb =
      (const unsigned char*)((typep[0] == 1 && layer > 0) ? pks : pkc);
  const unsigned short* ptg = Pt + (size_t)bh * NDK * NS;
  const float* s2b = s2a + (size_t)bh * NS;

  bf16x8 ones;
#pragma unroll
  for (int e = 0; e < 8; ++e) ones[e] = (short)0x3F80;     // bf16 1.0

  int rbase = iq * 256 + w * 16;
  float s1v = s1a[(size_t)bh * NS + rbase + il];
  const unsigned char* mrow = pkb + (((size_t)(b * NS + rbase + il) * NS) >> 3);

  f32x4 acc0 = {}, acc1 = {}, accd = {};

  for (int jh = 0; jh < 2; ++jh) {
    __syncthreads();
    // stage Pt half-slab (32 rows x 512 cols bf16 = 32KB), swizzled
    {
      const char* srcb = (const char*)ptg;
#pragma unroll
      for (int q = 0; q < 2; ++q) {
        int pos = q * 16384 + t * 16;         // 0..32767
        int r = pos >> 10;                    // row 0..31
        int incol = pos & 1023;               // byte within half-row
        uint4 v = *(const uint4*)(srcb + r * 2048 + jh * 1024 + incol);
        *(uint4*)((char*)ptl + r * 1024 + (incol ^ ((r & 7) << 4))) = v;
      }
      if (jh == 0 && t < 256)
        ((f32x4*)s2l)[t] = *(const f32x4*)(s2b + t * 4);
    }
    __syncthreads();

    for (int jg = 0; jg < 512; jg += 128) {
      uint4 mk = *(const uint4*)(mrow + ((jh * 512 + jg) >> 3));  // 128 j-bits
#pragma unroll
      for (int s = 0; s < 4; ++s) {
        unsigned int mword = (&mk.x)[s];
        unsigned int mb = (mword >> (g4 * 8)) & 0xFFu;
        int jl = jg + s * 32 + g4 * 8;                    // local col in half
        int coff = (jl * 2) ^ xorv;
        const char* prow = (const char*)ptl + il * 1024;
        bf16x8 b0 = *(const bf16x8*)(prow + coff);
        bf16x8 b1 = *(const bf16x8*)(prow + 16 * 1024 + coff);
        f32x4 sL = *(const f32x4*)&s2l[jh * 512 + jl];
        f32x4 sH = *(const f32x4*)&s2l[jh * 512 + jl + 4];
        float s2v[8] = {sL[0], sL[1], sL[2], sL[3],
                        sH[0], sH[1], sH[2], sH[3]};
        bf16x8 af;
#pragma unroll
        for (int e = 0; e < 8; ++e) {
          float sc = s1v + s2v[e];
          sc = fmaxf(sc, 0.2f * sc);           // LeakyReLU(0.2)
          float ex = EXP2F(sc);                // pre-scaled by log2e
          ex = (mb & (1u << e)) ? 0.f : ex;
          af[e] = (short)__bfloat16_as_ushort(__float2bfloat16(ex));
        }
        acc0 = __builtin_amdgcn_mfma_f32_16x16x32_bf16(af, b0, acc0, 0, 0, 0);
        acc1 = __builtin_amdgcn_mfma_f32_16x16x32_bf16(af, b1, acc1, 0, 0, 0);
        accd = __builtin_amdgcn_mfma_f32_16x16x32_bf16(af, ones, accd, 0, 0, 0);
      }
    }
  }

  // normalize + store concat (D layout: col=il, row=g4*4+e)
  {
    f32x4 rd;
#pragma unroll
    for (int e = 0; e < 4; ++e) rd[e] = __builtin_amdgcn_rcpf(accd[e]);
    float* cob = co + (size_t)(b * NS + rbase + g4 * 4) * NM + h * 32 + il;
#pragma unroll
    for (int e = 0; e < 4; ++e) {
      cob[(size_t)e * NM] = acc0[e] * rd[e];
      cob[(size_t)e * NM + 16] = acc1[e] * rd[e];
    }
  }
}

// ---------------------------------------------------------------------------
// Residual + LayerNorm: row r -> LN(xin[r] + co[r]) * g + b.
__global__ __launch_bounds__(256) void ln_kernel(
    const float* __restrict__ xin, const float* __restrict__ co,
    const float* __restrict__ lng, const float* __restrict__ lnb,
    float* __restrict__ xout)
{
  int row = blockIdx.x * 4 + (threadIdx.x >> 6);
  int lane = threadIdx.x & 63;
  size_t base = (size_t)row * NM + lane * 4;
  f32x4 cv = *(const f32x4*)(co + base);
  f32x4 xv = *(const f32x4*)(xin + base);
  f32x4 r;
#pragma unroll
  for (int e = 0; e < 4; ++e) r[e] = cv[e] + xv[e];
  float sm = r[0] + r[1] + r[2] + r[3];
  float sq = r[0] * r[0] + r[1] * r[1] + r[2] * r[2] + r[3] * r[3];
#pragma unroll
  for (int off = 32; off >= 1; off >>= 1) {
    sm += __shfl_xor(sm, off, 64);
    sq += __shfl_xor(sq, off, 64);
  }
  float mu = sm * (1.f / 256.f);
  float var = sq * (1.f / 256.f) - mu * mu;
  float inv = rsqrtf(var + 1e-5f);
  f32x4 gv = *(const f32x4*)(lng + lane * 4);
  f32x4 bv = *(const f32x4*)(lnb + lane * 4);
  f32x4 o;
#pragma unroll
  for (int e = 0; e < 4; ++e) o[e] = (r[e] - mu) * inv * gv[e] + bv[e];
  *(f32x4*)(xout + base) = o;
}

// ---------------------------------------------------------------------------
extern "C" void kernel_launch(void* const* d_in, const int* in_sizes, int n_in,
                              void* d_out, int out_size, void* d_ws, size_t ws_size,
                              hipStream_t stream)
{
  const int* adj = (const int*)d_in[0];
  const float* inputs = (const float*)d_in[1];
  const int* smask = (const int*)d_in[2];
  const int* typep = (const int*)d_in[3];
  const float* proj_w = (const float*)d_in[4];
  const float* proj_b = (const float*)d_in[5];
  const float* attn_w = (const float*)d_in[6];
  const float* attn_b = (const float*)d_in[7];
  const float* ln_g = (const float*)d_in[8];
  const float* ln_b = (const float*)d_in[9];
  float* out = (float*)d_out;

  char* ws = (char*)d_ws;
  unsigned int* pkc = (unsigned int*)(ws);                      // 2 MB
  unsigned int* pks = (unsigned int*)(ws + (2u << 20));         // 2 MB
  unsigned short* Pt = (unsigned short*)(ws + (4u << 20));      // 8 MB
  float* s1 = (float*)(ws + (12u << 20));                       // 512 KB
  float* s2 = (float*)(ws + (12u << 20) + (1u << 19));          // 512 KB
  float* x1 = (float*)(ws + (13u << 20));                       // 16 MB
  float* co = out;   // d_out doubles as concat scratch (fully overwritten)

  maskpack_kernel<<<2048, 256, 0, stream>>>(adj, smask, pkc, pks);

  for (int l = 0; l < NL; ++l) {
    const float* xin = (l == 0) ? inputs : x1;
    float* xout = (l == NL - 1) ? out : x1;
    proj_kernel<<<dim3(4, 256), 256, 0, stream>>>(
        xin, proj_w + (size_t)l * NH * NM * NDK, proj_b + (size_t)l * NH * NDK, Pt);
    s_kernel<<<512, 256, 0, stream>>>(Pt, attn_w + l * 64, attn_b + l, s1, s2);
    attn_kernel<<<512, 1024, 0, stream>>>(
        Pt, s1, s2, pkc, pks, typep, l, co);
    ln_kernel<<<4096, 256, 0, stream>>>(xin, co, ln_g + l * NM, ln_b + l * NM, xout);
  }
}

// Round 9
// 159.301 us; speedup vs baseline: 1.6962x; 1.0278x over previous
//
#include <hip/hip_runtime.h>
#include <hip/hip_bf16.h>
#include <math.h>

#define NB 16
#define NS 1024
#define NM 256
#define NH 8
#define NDK 32
#define NL 2

typedef __attribute__((ext_vector_type(4))) float f32x4;
typedef __attribute__((ext_vector_type(8))) short bf16x8;
typedef __attribute__((ext_vector_type(4))) short bf16x4u;

#if __has_builtin(__builtin_amdgcn_exp2f)
#define EXP2F(x) __builtin_amdgcn_exp2f(x)
#else
#define EXP2F(x) exp2f(x)
#endif

__device__ __forceinline__ unsigned short f2bf(float f) {
  unsigned int u = __builtin_bit_cast(unsigned int, f);
  unsigned int r = u + 0x7fffu + ((u >> 16) & 1u);
  return (unsigned short)(r >> 16);
}
__device__ __forceinline__ float bf2f(unsigned short h) {
  unsigned int u = ((unsigned int)h) << 16;
  return __builtin_bit_cast(float, u);
}

// ---------------------------------------------------------------------------
// Pack (smask || adj==0) and (smask) into bitmasks, 1 bit per (b,i,j).
__global__ __launch_bounds__(256) void maskpack_kernel(
    const int* __restrict__ adj, const int* __restrict__ sm,
    unsigned int* __restrict__ pkc, unsigned int* __restrict__ pks)
{
  int t = blockIdx.x * 256 + threadIdx.x;
  long base = (long)t * 32;
  const int4* a4 = (const int4*)(adj + base);
  const int4* m4 = (const int4*)(sm + base);
  union { int4 v[8]; int b[32]; } au, mu;
#pragma unroll
  for (int q = 0; q < 8; ++q) { au.v[q] = a4[q]; mu.v[q] = m4[q]; }
  unsigned int wc = 0, wsb = 0;
#pragma unroll
  for (int e = 0; e < 32; ++e) {
    unsigned int msk = mu.b[e] ? 1u : 0u;
    unsigned int cmb = (mu.b[e] || au.b[e] == 0) ? 1u : 0u;
    wsb |= msk << e;
    wc  |= cmb << e;
  }
  pkc[t] = wc; pks[t] = wsb;
}

// ---------------------------------------------------------------------------
// Projection GEMM -> Pt[b][h][d][s] (bf16), 64x64 tile, 4 waves.
__global__ __launch_bounds__(256) void proj_kernel(
    const float* __restrict__ x,        // (B*S, M)
    const float* __restrict__ pw,       // (H, M, DK) this layer
    const float* __restrict__ pb,       // (H*DK)
    unsigned short* __restrict__ Pt)    // (B,H,DK,S)
{
  __shared__ unsigned short As[64][40];
  __shared__ unsigned short Bs[64][40];

  int ct = blockIdx.x;
  int rt = blockIdx.y;
  int t = threadIdx.x;
  int w = t >> 6, lane = t & 63;
  int il = lane & 15, g4 = lane >> 4;
  int wi = w >> 1, wc = w & 1;

  f32x4 acc[2][2] = {};

  int arow = t >> 2, akoff = (t & 3) * 8;
  int bcol = t & 63, bk0 = (t >> 6) * 8;
  int hd = ct * 64 + bcol;
  int h = hd >> 5, d = hd & 31;

  for (int k0 = 0; k0 < NM; k0 += 32) {
    const float* xp = x + (size_t)(rt * 64 + arow) * NM + k0 + akoff;
    f32x4 v0 = *(const f32x4*)xp;
    f32x4 v1 = *(const f32x4*)(xp + 4);
    bf16x8 av;
    av[0] = f2bf(v0[0]); av[1] = f2bf(v0[1]); av[2] = f2bf(v0[2]); av[3] = f2bf(v0[3]);
    av[4] = f2bf(v1[0]); av[5] = f2bf(v1[1]); av[6] = f2bf(v1[2]); av[7] = f2bf(v1[3]);
    *(bf16x8*)&As[arow][akoff] = av;
    const float* wp = pw + (size_t)h * NM * NDK + (size_t)(k0 + bk0) * NDK + d;
    bf16x8 bv;
#pragma unroll
    for (int q = 0; q < 8; ++q) bv[q] = f2bf(wp[q * NDK]);
    *(bf16x8*)&Bs[bcol][bk0] = bv;
    __syncthreads();

    bf16x8 af0 = *(bf16x8*)&As[wi * 32 + il][g4 * 8];
    bf16x8 af1 = *(bf16x8*)&As[wi * 32 + 16 + il][g4 * 8];
    bf16x8 bf0 = *(bf16x8*)&Bs[wc * 32 + il][g4 * 8];
    bf16x8 bf1 = *(bf16x8*)&Bs[wc * 32 + 16 + il][g4 * 8];
    acc[0][0] = __builtin_amdgcn_mfma_f32_16x16x32_bf16(af0, bf0, acc[0][0], 0, 0, 0);
    acc[0][1] = __builtin_amdgcn_mfma_f32_16x16x32_bf16(af0, bf1, acc[0][1], 0, 0, 0);
    acc[1][0] = __builtin_amdgcn_mfma_f32_16x16x32_bf16(af1, bf0, acc[1][0], 0, 0, 0);
    acc[1][1] = __builtin_amdgcn_mfma_f32_16x16x32_bf16(af1, bf1, acc[1][1], 0, 0, 0);
    __syncthreads();
  }

#pragma unroll
  for (int ih = 0; ih < 2; ++ih) {
#pragma unroll
    for (int dh = 0; dh < 2; ++dh) {
      int colhd = ct * 64 + wc * 32 + dh * 16 + il;
      int hh = colhd >> 5, dd = colhd & 31;
      float bias = pb[colhd];
      int r0 = rt * 64 + wi * 32 + ih * 16 + g4 * 4;
      int bb = r0 >> 10, ss = r0 & 1023;
      f32x4 c = acc[ih][dh];
      unsigned short ov[4];
#pragma unroll
      for (int e = 0; e < 4; ++e) ov[e] = f2bf(c[e] + bias);
      size_t idx = ((size_t)(bb * NH + hh) * NDK + dd) * NS + ss;
      *(bf16x4u*)(Pt + idx) = *(bf16x4u*)ov;
    }
  }
}

// ---------------------------------------------------------------------------
// s1 raw (log2e-scaled); s2 factored: s2p = exp2(s2L), s2n = exp2(0.2*s2L).
__global__ __launch_bounds__(256) void s_kernel(
    const unsigned short* __restrict__ Pt,
    const float* __restrict__ aw,   // 64 floats this layer
    const float* __restrict__ abp,  // attn_b + l
    float* __restrict__ s1o, float* __restrict__ s2po, float* __restrict__ s2no)
{
  const float LOG2E = 1.4426950408889634f;
  int t = blockIdx.x * 256 + threadIdx.x;   // (b*H+h)*S + s
  int bh = t >> 10, s = t & 1023;
  const unsigned short* p = Pt + (size_t)bh * NDK * NS + s;
  float s1 = 0.f, s2 = 0.f;
#pragma unroll
  for (int dd = 0; dd < NDK; ++dd) {
    float pv = bf2f(p[dd * NS]);
    s1 += pv * aw[dd];
    s2 += pv * aw[32 + dd];
  }
  float s2L = (s2 + abp[0]) * LOG2E;
  s2L = fminf(fmaxf(s2L, -30.f), 30.f);
  s1o[t] = s1 * LOG2E;
  s2po[t] = EXP2F(s2L);
  s2no[t] = EXP2F(0.2f * s2L);
}

// ---------------------------------------------------------------------------
// Attention with LDS-staged Pt and FACTORED exp weights:
//   score>=0: w = E1p*E2p ; score<0: w = E1n*E2n ; branch: E2p >= exp2(-s1).
// No per-element transcendentals. Block = (b, head, i-quarter), 16 waves;
// wave w owns 16 rows. Pt staged in two 32KB swizzled j-halves.
__global__ __launch_bounds__(1024, 8) void attn_kernel(
    const unsigned short* __restrict__ Pt,    // (B,H,DK,S) bf16
    const float* __restrict__ s1a,            // (B,H,S), log2e-scaled
    const float* __restrict__ s2pa,           // exp2(s2L)
    const float* __restrict__ s2na,           // exp2(0.2*s2L)
    const unsigned int* __restrict__ pkc,     // combined mask bits
    const unsigned int* __restrict__ pks,     // smask-only bits
    const int* __restrict__ typep,
    int layer,
    float* __restrict__ co)                   // (B,S,M) f32 concat out
{
  __shared__ __align__(16) unsigned short ptl[32 * 512];  // 32KB, swizzled
  __shared__ float s2pl[1024];                            // 4KB
  __shared__ float s2nl[1024];                            // 4KB

  // XCD chunk swizzle: 64 consecutive logical blocks (2 batches) per XCD.
  int orig = blockIdx.x;
  int lb = (orig & 7) * 64 + (orig >> 3);
  int iq = lb & 3, bh = lb >> 2;
  int b = bh >> 3, h = bh & 7;

  int t = threadIdx.x, w = t >> 6, lane = t & 63;
  int il = lane & 15, g4 = lane >> 4;
  int xorv = (il & 7) << 4;

  const unsigned char* pkb =
      (const unsigned char*)((typep[0] == 1 && layer > 0) ? pks : pkc);
  const unsigned short* ptg = Pt + (size_t)bh * NDK * NS;

  bf16x8 ones;
#pragma unroll
  for (int e = 0; e < 8; ++e) ones[e] = (short)0x3F80;     // bf16 1.0

  int rbase = iq * 256 + w * 16;
  float s1L = s1a[(size_t)bh * NS + rbase + il];
  s1L = fminf(fmaxf(s1L, -30.f), 30.f);
  float e1p = EXP2F(s1L);
  float e1n = EXP2F(0.2f * s1L);
  float rcp1p = EXP2F(-s1L);
  const unsigned char* mrow = pkb + (((size_t)(b * NS + rbase + il) * NS) >> 3);

  f32x4 acc0 = {}, acc1 = {}, accd = {};

  for (int jh = 0; jh < 2; ++jh) {
    __syncthreads();
    // stage Pt half-slab (32 rows x 512 cols bf16 = 32KB), swizzled
    {
      const char* srcb = (const char*)ptg;
#pragma unroll
      for (int q = 0; q < 2; ++q) {
        int pos = q * 16384 + t * 16;         // 0..32767
        int r = pos >> 10;                    // row 0..31
        int incol = pos & 1023;               // byte within half-row
        uint4 v = *(const uint4*)(srcb + r * 2048 + jh * 1024 + incol);
        *(uint4*)((char*)ptl + r * 1024 + (incol ^ ((r & 7) << 4))) = v;
      }
      if (jh == 0) {
        if (t < 256)
          ((f32x4*)s2pl)[t] = *(const f32x4*)(s2pa + (size_t)bh * NS + t * 4);
        else if (t < 512)
          ((f32x4*)s2nl)[t - 256] =
              *(const f32x4*)(s2na + (size_t)bh * NS + (t - 256) * 4);
      }
    }
    __syncthreads();

    for (int jg = 0; jg < 512; jg += 128) {
      uint4 mk = *(const uint4*)(mrow + ((jh * 512 + jg) >> 3));  // 128 j-bits
#pragma unroll
      for (int s = 0; s < 4; ++s) {
        unsigned int mword = (&mk.x)[s];
        unsigned int mb = (mword >> (g4 * 8)) & 0xFFu;
        int jl = jg + s * 32 + g4 * 8;                    // local col in half
        int coff = (jl * 2) ^ xorv;
        const char* prow = (const char*)ptl + il * 1024;
        bf16x8 b0 = *(const bf16x8*)(prow + coff);
        bf16x8 b1 = *(const bf16x8*)(prow + 16 * 1024 + coff);
        int jfull = jh * 512 + jl;
        f32x4 pL = *(const f32x4*)&s2pl[jfull];
        f32x4 pH = *(const f32x4*)&s2pl[jfull + 4];
        f32x4 nL = *(const f32x4*)&s2nl[jfull];
        f32x4 nH = *(const f32x4*)&s2nl[jfull + 4];
        float e2p[8] = {pL[0], pL[1], pL[2], pL[3], pH[0], pH[1], pH[2], pH[3]};
        float e2n[8] = {nL[0], nL[1], nL[2], nL[3], nH[0], nH[1], nH[2], nH[3]};
        bf16x8 af;
#pragma unroll
        for (int e = 0; e < 8; ++e) {
          bool c = e2p[e] >= rcp1p;            // score >= 0 branch?
          float wv = (c ? e1p : e1n) * (c ? e2p[e] : e2n[e]);
          wv = (mb & (1u << e)) ? 0.f : wv;
          af[e] = (short)__bfloat16_as_ushort(__float2bfloat16(wv));
        }
        acc0 = __builtin_amdgcn_mfma_f32_16x16x32_bf16(af, b0, acc0, 0, 0, 0);
        acc1 = __builtin_amdgcn_mfma_f32_16x16x32_bf16(af, b1, acc1, 0, 0, 0);
        accd = __builtin_amdgcn_mfma_f32_16x16x32_bf16(af, ones, accd, 0, 0, 0);
      }
    }
  }

  // normalize + store concat (D layout: col=il, row=g4*4+e)
  {
    f32x4 rd;
#pragma unroll
    for (int e = 0; e < 4; ++e) rd[e] = __builtin_amdgcn_rcpf(accd[e]);
    float* cob = co + (size_t)(b * NS + rbase + g4 * 4) * NM + h * 32 + il;
#pragma unroll
    for (int e = 0; e < 4; ++e) {
      cob[(size_t)e * NM] = acc0[e] * rd[e];
      cob[(size_t)e * NM + 16] = acc1[e] * rd[e];
    }
  }
}

// ---------------------------------------------------------------------------
// Residual + LayerNorm: row r -> LN(xin[r] + co[r]) * g + b.
__global__ __launch_bounds__(256) void ln_kernel(
    const float* __restrict__ xin, const float* __restrict__ co,
    const float* __restrict__ lng, const float* __restrict__ lnb,
    float* __restrict__ xout)
{
  int row = blockIdx.x * 4 + (threadIdx.x >> 6);
  int lane = threadIdx.x & 63;
  size_t base = (size_t)row * NM + lane * 4;
  f32x4 cv = *(const f32x4*)(co + base);
  f32x4 xv = *(const f32x4*)(xin + base);
  f32x4 r;
#pragma unroll
  for (int e = 0; e < 4; ++e) r[e] = cv[e] + xv[e];
  float sm = r[0] + r[1] + r[2] + r[3];
  float sq = r[0] * r[0] + r[1] * r[1] + r[2] * r[2] + r[3] * r[3];
#pragma unroll
  for (int off = 32; off >= 1; off >>= 1) {
    sm += __shfl_xor(sm, off, 64);
    sq += __shfl_xor(sq, off, 64);
  }
  float mu = sm * (1.f / 256.f);
  float var = sq * (1.f / 256.f) - mu * mu;
  float inv = rsqrtf(var + 1e-5f);
  f32x4 gv = *(const f32x4*)(lng + lane * 4);
  f32x4 bv = *(const f32x4*)(lnb + lane * 4);
  f32x4 o;
#pragma unroll
  for (int e = 0; e < 4; ++e) o[e] = (r[e] - mu) * inv * gv[e] + bv[e];
  *(f32x4*)(xout + base) = o;
}

// ---------------------------------------------------------------------------
extern "C" void kernel_launch(void* const* d_in, const int* in_sizes, int n_in,
                              void* d_out, int out_size, void* d_ws, size_t ws_size,
                              hipStream_t stream)
{
  const int* adj = (const int*)d_in[0];
  const float* inputs = (const float*)d_in[1];
  const int* smask = (const int*)d_in[2];
  const int* typep = (const int*)d_in[3];
  const float* proj_w = (const float*)d_in[4];
  const float* proj_b = (const float*)d_in[5];
  const float* attn_w = (const float*)d_in[6];
  const float* attn_b = (const float*)d_in[7];
  const float* ln_g = (const float*)d_in[8];
  const float* ln_b = (const float*)d_in[9];
  float* out = (float*)d_out;

  char* ws = (char*)d_ws;
  unsigned int* pkc = (unsigned int*)(ws);                      // 2 MB
  unsigned int* pks = (unsigned int*)(ws + (2u << 20));         // 2 MB
  unsigned short* Pt = (unsigned short*)(ws + (4u << 20));      // 8 MB
  float* s1 = (float*)(ws + (12u << 20));                       // 512 KB
  float* s2p = (float*)(ws + (12u << 20) + (1u << 19));         // 512 KB
  float* s2n = (float*)(ws + (13u << 20));                      // 512 KB
  float* x1 = (float*)(ws + (14u << 20));                       // 16 MB
  float* co = out;   // d_out doubles as concat scratch (fully overwritten)

  maskpack_kernel<<<2048, 256, 0, stream>>>(adj, smask, pkc, pks);

  for (int l = 0; l < NL; ++l) {
    const float* xin = (l == 0) ? inputs : x1;
    float* xout = (l == NL - 1) ? out : x1;
    proj_kernel<<<dim3(4, 256), 256, 0, stream>>>(
        xin, proj_w + (size_t)l * NH * NM * NDK, proj_b + (size_t)l * NH * NDK, Pt);
    s_kernel<<<512, 256, 0, stream>>>(Pt, attn_w + l * 64, attn_b + l, s1, s2p, s2n);
    attn_kernel<<<512, 1024, 0, stream>>>(
        Pt, s1, s2p, s2n, pkc, pks, typep, l, co);
    ln_kernel<<<4096, 256, 0, stream>>>(xin, co, ln_g + l * NM, ln_b + l * NM, xout);
  }
}

// Round 10
// 157.425 us; speedup vs baseline: 1.7164x; 1.0119x over previous
//
#include <hip/hip_runtime.h>
#include <hip/hip_bf16.h>
#include <math.h>

#define NB 16
#define NS 1024
#define NM 256
#define NH 8
#define NDK 32
#define NL 2

typedef __attribute__((ext_vector_type(4))) float f32x4;
typedef __attribute__((ext_vector_type(8))) short bf16x8;
typedef __attribute__((ext_vector_type(4))) short bf16x4u;

#if __has_builtin(__builtin_amdgcn_exp2f)
#define EXP2F(x) __builtin_amdgcn_exp2f(x)
#else
#define EXP2F(x) exp2f(x)
#endif

__device__ __forceinline__ unsigned short f2bf(float f) {
  unsigned int u = __builtin_bit_cast(unsigned int, f);
  unsigned int r = u + 0x7fffu + ((u >> 16) & 1u);
  return (unsigned short)(r >> 16);
}
__device__ __forceinline__ float bf2f(unsigned short h) {
  unsigned int u = ((unsigned int)h) << 16;
  return __builtin_bit_cast(float, u);
}

// ---------------------------------------------------------------------------
// Pack (smask || adj==0) and (smask) into bitmasks, 1 bit per (b,i,j).
// Wave-coalesced: step k, lane l loads int4 at element k*256+l*4 (1KB/wave
// contiguous). Nibbles assembled into 32-bit words via 3-level shfl_xor OR.
__global__ __launch_bounds__(256) void maskpack_kernel(
    const int* __restrict__ adj, const int* __restrict__ sm,
    unsigned int* __restrict__ pkc, unsigned int* __restrict__ pks)
{
  int wave_id = blockIdx.x * 4 + (threadIdx.x >> 6);
  int lane = threadIdx.x & 63;
  size_t eb = (size_t)wave_id * 2048;          // element base for this wave
  const int4* a4 = (const int4*)(adj + eb);
  const int4* m4 = (const int4*)(sm + eb);
  int lg = lane >> 3;                           // word group 0..7
  int sh = (lane & 7) * 4;                      // nibble position
#pragma unroll
  for (int k = 0; k < 8; ++k) {
    int idx = k * 64 + lane;
    int4 av = a4[idx];
    int4 mv = m4[idx];
    unsigned int nc = 0, ns = 0;
    nc |= ((mv.x || av.x == 0) ? 1u : 0u);
    nc |= ((mv.y || av.y == 0) ? 2u : 0u);
    nc |= ((mv.z || av.z == 0) ? 4u : 0u);
    nc |= ((mv.w || av.w == 0) ? 8u : 0u);
    ns |= (mv.x ? 1u : 0u) | (mv.y ? 2u : 0u) | (mv.z ? 4u : 0u) | (mv.w ? 8u : 0u);
    unsigned int vc = nc << sh, vs = ns << sh;
    vc |= __shfl_xor(vc, 1, 64);  vs |= __shfl_xor(vs, 1, 64);
    vc |= __shfl_xor(vc, 2, 64);  vs |= __shfl_xor(vs, 2, 64);
    vc |= __shfl_xor(vc, 4, 64);  vs |= __shfl_xor(vs, 4, 64);
    if ((lane & 7) == 0) {
      size_t wi = (size_t)wave_id * 64 + k * 8 + lg;
      pkc[wi] = vc;
      pks[wi] = vs;
    }
  }
}

// ---------------------------------------------------------------------------
// Projection GEMM -> Pt[b][h][d][s] (bf16), 64x64 tile, 4 waves.
__global__ __launch_bounds__(256) void proj_kernel(
    const float* __restrict__ x,        // (B*S, M)
    const float* __restrict__ pw,       // (H, M, DK) this layer
    const float* __restrict__ pb,       // (H*DK)
    unsigned short* __restrict__ Pt)    // (B,H,DK,S)
{
  __shared__ unsigned short As[64][40];
  __shared__ unsigned short Bs[64][40];

  int ct = blockIdx.x;
  int rt = blockIdx.y;
  int t = threadIdx.x;
  int w = t >> 6, lane = t & 63;
  int il = lane & 15, g4 = lane >> 4;
  int wi = w >> 1, wc = w & 1;

  f32x4 acc[2][2] = {};

  int arow = t >> 2, akoff = (t & 3) * 8;
  int bcol = t & 63, bk0 = (t >> 6) * 8;
  int hd = ct * 64 + bcol;
  int h = hd >> 5, d = hd & 31;

  for (int k0 = 0; k0 < NM; k0 += 32) {
    const float* xp = x + (size_t)(rt * 64 + arow) * NM + k0 + akoff;
    f32x4 v0 = *(const f32x4*)xp;
    f32x4 v1 = *(const f32x4*)(xp + 4);
    bf16x8 av;
    av[0] = f2bf(v0[0]); av[1] = f2bf(v0[1]); av[2] = f2bf(v0[2]); av[3] = f2bf(v0[3]);
    av[4] = f2bf(v1[0]); av[5] = f2bf(v1[1]); av[6] = f2bf(v1[2]); av[7] = f2bf(v1[3]);
    *(bf16x8*)&As[arow][akoff] = av;
    const float* wp = pw + (size_t)h * NM * NDK + (size_t)(k0 + bk0) * NDK + d;
    bf16x8 bv;
#pragma unroll
    for (int q = 0; q < 8; ++q) bv[q] = f2bf(wp[q * NDK]);
    *(bf16x8*)&Bs[bcol][bk0] = bv;
    __syncthreads();

    bf16x8 af0 = *(bf16x8*)&As[wi * 32 + il][g4 * 8];
    bf16x8 af1 = *(bf16x8*)&As[wi * 32 + 16 + il][g4 * 8];
    bf16x8 bf0 = *(bf16x8*)&Bs[wc * 32 + il][g4 * 8];
    bf16x8 bf1 = *(bf16x8*)&Bs[wc * 32 + 16 + il][g4 * 8];
    acc[0][0] = __builtin_amdgcn_mfma_f32_16x16x32_bf16(af0, bf0, acc[0][0], 0, 0, 0);
    acc[0][1] = __builtin_amdgcn_mfma_f32_16x16x32_bf16(af0, bf1, acc[0][1], 0, 0, 0);
    acc[1][0] = __builtin_amdgcn_mfma_f32_16x16x32_bf16(af1, bf0, acc[1][0], 0, 0, 0);
    acc[1][1] = __builtin_amdgcn_mfma_f32_16x16x32_bf16(af1, bf1, acc[1][1], 0, 0, 0);
    __syncthreads();
  }

#pragma unroll
  for (int ih = 0; ih < 2; ++ih) {
#pragma unroll
    for (int dh = 0; dh < 2; ++dh) {
      int colhd = ct * 64 + wc * 32 + dh * 16 + il;
      int hh = colhd >> 5, dd = colhd & 31;
      float bias = pb[colhd];
      int r0 = rt * 64 + wi * 32 + ih * 16 + g4 * 4;
      int bb = r0 >> 10, ss = r0 & 1023;
      f32x4 c = acc[ih][dh];
      unsigned short ov[4];
#pragma unroll
      for (int e = 0; e < 4; ++e) ov[e] = f2bf(c[e] + bias);
      size_t idx = ((size_t)(bb * NH + hh) * NDK + dd) * NS + ss;
      *(bf16x4u*)(Pt + idx) = *(bf16x4u*)ov;
    }
  }
}

// ---------------------------------------------------------------------------
// s1 raw (log2e-scaled); s2 factored: s2p = exp2(s2L), s2n = exp2(0.2*s2L).
__global__ __launch_bounds__(256) void s_kernel(
    const unsigned short* __restrict__ Pt,
    const float* __restrict__ aw,   // 64 floats this layer
    const float* __restrict__ abp,  // attn_b + l
    float* __restrict__ s1o, float* __restrict__ s2po, float* __restrict__ s2no)
{
  const float LOG2E = 1.4426950408889634f;
  int t = blockIdx.x * 256 + threadIdx.x;   // (b*H+h)*S + s
  int bh = t >> 10, s = t & 1023;
  const unsigned short* p = Pt + (size_t)bh * NDK * NS + s;
  float s1 = 0.f, s2 = 0.f;
#pragma unroll
  for (int dd = 0; dd < NDK; ++dd) {
    float pv = bf2f(p[dd * NS]);
    s1 += pv * aw[dd];
    s2 += pv * aw[32 + dd];
  }
  float s2L = (s2 + abp[0]) * LOG2E;
  s2L = fminf(fmaxf(s2L, -30.f), 30.f);
  s1o[t] = s1 * LOG2E;
  s2po[t] = EXP2F(s2L);
  s2no[t] = EXP2F(0.2f * s2L);
}

// ---------------------------------------------------------------------------
// Attention with LDS-staged Pt and FACTORED exp weights:
//   score>=0: w = E1p*E2p ; score<0: w = E1n*E2n ; branch: E2p >= exp2(-s1).
// No per-element transcendentals. Block = (b, head, i-quarter), 16 waves;
// wave w owns 16 rows. Pt staged in two 32KB swizzled j-halves.
__global__ __launch_bounds__(1024, 8) void attn_kernel(
    const unsigned short* __restrict__ Pt,    // (B,H,DK,S) bf16
    const float* __restrict__ s1a,            // (B,H,S), log2e-scaled
    const float* __restrict__ s2pa,           // exp2(s2L)
    const float* __restrict__ s2na,           // exp2(0.2*s2L)
    const unsigned int* __restrict__ pkc,     // combined mask bits
    const unsigned int* __restrict__ pks,     // smask-only bits
    const int* __restrict__ typep,
    int layer,
    float* __restrict__ co)                   // (B,S,M) f32 concat out
{
  __shared__ __align__(16) unsigned short ptl[32 * 512];  // 32KB, swizzled
  __shared__ float s2pl[1024];                            // 4KB
  __shared__ float s2nl[1024];                            // 4KB

  // XCD chunk swizzle: 64 consecutive logical blocks (2 batches) per XCD.
  int orig = blockIdx.x;
  int lb = (orig & 7) * 64 + (orig >> 3);
  int iq = lb & 3, bh = lb >> 2;
  int b = bh >> 3, h = bh & 7;

  int t = threadIdx.x, w = t >> 6, lane = t & 63;
  int il = lane & 15, g4 = lane >> 4;
  int xorv = (il & 7) << 4;

  const unsigned char* pkb =
      (const unsigned char*)((typep[0] == 1 && layer > 0) ? pks : pkc);
  const unsigned short* ptg = Pt + (size_t)bh * NDK * NS;

  bf16x8 ones;
#pragma unroll
  for (int e = 0; e < 8; ++e) ones[e] = (short)0x3F80;     // bf16 1.0

  int rbase = iq * 256 + w * 16;
  float s1L = s1a[(size_t)bh * NS + rbase + il];
  s1L = fminf(fmaxf(s1L, -30.f), 30.f);
  float e1p = EXP2F(s1L);
  float e1n = EXP2F(0.2f * s1L);
  float rcp1p = EXP2F(-s1L);
  const unsigned char* mrow = pkb + (((size_t)(b * NS + rbase + il) * NS) >> 3);

  f32x4 acc0 = {}, acc1 = {}, accd = {};

  for (int jh = 0; jh < 2; ++jh) {
    __syncthreads();
    // stage Pt half-slab (32 rows x 512 cols bf16 = 32KB), swizzled
    {
      const char* srcb = (const char*)ptg;
#pragma unroll
      for (int q = 0; q < 2; ++q) {
        int pos = q * 16384 + t * 16;         // 0..32767
        int r = pos >> 10;                    // row 0..31
        int incol = pos & 1023;               // byte within half-row
        uint4 v = *(const uint4*)(srcb + r * 2048 + jh * 1024 + incol);
        *(uint4*)((char*)ptl + r * 1024 + (incol ^ ((r & 7) << 4))) = v;
      }
      if (jh == 0) {
        if (t < 256)
          ((f32x4*)s2pl)[t] = *(const f32x4*)(s2pa + (size_t)bh * NS + t * 4);
        else if (t < 512)
          ((f32x4*)s2nl)[t - 256] =
              *(const f32x4*)(s2na + (size_t)bh * NS + (t - 256) * 4);
      }
    }
    __syncthreads();

    for (int jg = 0; jg < 512; jg += 128) {
      uint4 mk = *(const uint4*)(mrow + ((jh * 512 + jg) >> 3));  // 128 j-bits
#pragma unroll
      for (int s = 0; s < 4; ++s) {
        unsigned int mword = (&mk.x)[s];
        unsigned int mb = (mword >> (g4 * 8)) & 0xFFu;
        int jl = jg + s * 32 + g4 * 8;                    // local col in half
        int coff = (jl * 2) ^ xorv;
        const char* prow = (const char*)ptl + il * 1024;
        bf16x8 b0 = *(const bf16x8*)(prow + coff);
        bf16x8 b1 = *(const bf16x8*)(prow + 16 * 1024 + coff);
        int jfull = jh * 512 + jl;
        f32x4 pL = *(const f32x4*)&s2pl[jfull];
        f32x4 pH = *(const f32x4*)&s2pl[jfull + 4];
        f32x4 nL = *(const f32x4*)&s2nl[jfull];
        f32x4 nH = *(const f32x4*)&s2nl[jfull + 4];
        float e2p[8] = {pL[0], pL[1], pL[2], pL[3], pH[0], pH[1], pH[2], pH[3]};
        float e2n[8] = {nL[0], nL[1], nL[2], nL[3], nH[0], nH[1], nH[2], nH[3]};
        bf16x8 af;
#pragma unroll
        for (int e = 0; e < 8; ++e) {
          bool c = e2p[e] >= rcp1p;            // score >= 0 branch?
          float wv = (c ? e1p : e1n) * (c ? e2p[e] : e2n[e]);
          wv = (mb & (1u << e)) ? 0.f : wv;
          af[e] = (short)__bfloat16_as_ushort(__float2bfloat16(wv));
        }
        acc0 = __builtin_amdgcn_mfma_f32_16x16x32_bf16(af, b0, acc0, 0, 0, 0);
        acc1 = __builtin_amdgcn_mfma_f32_16x16x32_bf16(af, b1, acc1, 0, 0, 0);
        accd = __builtin_amdgcn_mfma_f32_16x16x32_bf16(af, ones, accd, 0, 0, 0);
      }
    }
  }

  // normalize + store concat (D layout: col=il, row=g4*4+e)
  {
    f32x4 rd;
#pragma unroll
    for (int e = 0; e < 4; ++e) rd[e] = __builtin_amdgcn_rcpf(accd[e]);
    float* cob = co + (size_t)(b * NS + rbase + g4 * 4) * NM + h * 32 + il;
#pragma unroll
    for (int e = 0; e < 4; ++e) {
      cob[(size_t)e * NM] = acc0[e] * rd[e];
      cob[(size_t)e * NM + 16] = acc1[e] * rd[e];
    }
  }
}

// ---------------------------------------------------------------------------
// Residual + LayerNorm: row r -> LN(xin[r] + co[r]) * g + b.
__global__ __launch_bounds__(256) void ln_kernel(
    const float* __restrict__ xin, const float* __restrict__ co,
    const float* __restrict__ lng, const float* __restrict__ lnb,
    float* __restrict__ xout)
{
  int row = blockIdx.x * 4 + (threadIdx.x >> 6);
  int lane = threadIdx.x & 63;
  size_t base = (size_t)row * NM + lane * 4;
  f32x4 cv = *(const f32x4*)(co + base);
  f32x4 xv = *(const f32x4*)(xin + base);
  f32x4 r;
#pragma unroll
  for (int e = 0; e < 4; ++e) r[e] = cv[e] + xv[e];
  float sm = r[0] + r[1] + r[2] + r[3];
  float sq = r[0] * r[0] + r[1] * r[1] + r[2] * r[2] + r[3] * r[3];
#pragma unroll
  for (int off = 32; off >= 1; off >>= 1) {
    sm += __shfl_xor(sm, off, 64);
    sq += __shfl_xor(sq, off, 64);
  }
  float mu = sm * (1.f / 256.f);
  float var = sq * (1.f / 256.f) - mu * mu;
  float inv = rsqrtf(var + 1e-5f);
  f32x4 gv = *(const f32x4*)(lng + lane * 4);
  f32x4 bv = *(const f32x4*)(lnb + lane * 4);
  f32x4 o;
#pragma unroll
  for (int e = 0; e < 4; ++e) o[e] = (r[e] - mu) * inv * gv[e] + bv[e];
  *(f32x4*)(xout + base) = o;
}

// ---------------------------------------------------------------------------
extern "C" void kernel_launch(void* const* d_in, const int* in_sizes, int n_in,
                              void* d_out, int out_size, void* d_ws, size_t ws_size,
                              hipStream_t stream)
{
  const int* adj = (const int*)d_in[0];
  const float* inputs = (const float*)d_in[1];
  const int* smask = (const int*)d_in[2];
  const int* typep = (const int*)d_in[3];
  const float* proj_w = (const float*)d_in[4];
  const float* proj_b = (const float*)d_in[5];
  const float* attn_w = (const float*)d_in[6];
  const float* attn_b = (const float*)d_in[7];
  const float* ln_g = (const float*)d_in[8];
  const float* ln_b = (const float*)d_in[9];
  float* out = (float*)d_out;

  char* ws = (char*)d_ws;
  unsigned int* pkc = (unsigned int*)(ws);                      // 2 MB
  unsigned int* pks = (unsigned int*)(ws + (2u << 20));         // 2 MB
  unsigned short* Pt = (unsigned short*)(ws + (4u << 20));      // 8 MB
  float* s1 = (float*)(ws + (12u << 20));                       // 512 KB
  float* s2p = (float*)(ws + (12u << 20) + (1u << 19));         // 512 KB
  float* s2n = (float*)(ws + (13u << 20));                      // 512 KB
  float* x1 = (float*)(ws + (14u << 20));                       // 16 MB
  float* co = out;   // d_out doubles as concat scratch (fully overwritten)

  maskpack_kernel<<<2048, 256, 0, stream>>>(adj, smask, pkc, pks);

  for (int l = 0; l < NL; ++l) {
    const float* xin = (l == 0) ? inputs : x1;
    float* xout = (l == NL - 1) ? out : x1;
    proj_kernel<<<dim3(4, 256), 256, 0, stream>>>(
        xin, proj_w + (size_t)l * NH * NM * NDK, proj_b + (size_t)l * NH * NDK, Pt);
    s_kernel<<<512, 256, 0, stream>>>(Pt, attn_w + l * 64, attn_b + l, s1, s2p, s2n);
    attn_kernel<<<512, 1024, 0, stream>>>(
        Pt, s1, s2p, s2n, pkc, pks, typep, l, co);
    ln_kernel<<<4096, 256, 0, stream>>>(xin, co, ln_g + l * NM, ln_b + l * NM, xout);
  }
}